// Round 1
// baseline (4996.119 us; speedup 1.0000x reference)
//
#include <hip/hip_runtime.h>
#include <hip/hip_bf16.h>
#include <math.h>

#define S_LEN 1024
#define E_DIM 512
#define I_DIM 1024
#define H_NUM 4
#define DH_   256
#define B_NUM 8
#define ROWS  (B_NUM*S_LEN)   // 8192

// ---------------- LayerNorm row stats (mean, rstd) ----------------
__global__ __launch_bounds__(256) void ln_stats_k(const float* __restrict__ x,
                                                  float* __restrict__ mu,
                                                  float* __restrict__ rstd) {
    int wave = threadIdx.x >> 6, lane = threadIdx.x & 63;
    int row  = blockIdx.x * 4 + wave;
    const float* xr = x + (size_t)row * E_DIM;
    float s = 0.f, s2 = 0.f;
#pragma unroll
    for (int q = 0; q < 2; q++) {
        float4 v = *(const float4*)&xr[lane * 4 + q * 256];
        s  += v.x + v.y + v.z + v.w;
        s2 += v.x*v.x + v.y*v.y + v.z*v.z + v.w*v.w;
    }
#pragma unroll
    for (int off = 32; off > 0; off >>= 1) {
        s  += __shfl_down(s, off);
        s2 += __shfl_down(s2, off);
    }
    if (lane == 0) {
        float m   = s * (1.f / E_DIM);
        float var = s2 * (1.f / E_DIM) - m * m;
        mu[row]   = m;
        rstd[row] = rsqrtf(var + 1e-5f);
    }
}

// ---------------- Generic fp32 tiled GEMM ----------------
// C[8192 x N] = op(A[8192 x K, lda]) @ W[K x N]  (+bias[n]) (+res[row,ldres])
// LNA: apply (a-mu)*rstd*g+b to A elements on load.
// EPI: 0 none, 1 +bias, 2 +bias+res
template<int LNA, int EPI>
__global__ __launch_bounds__(256) void gemm_k(
    const float* __restrict__ A, int lda,
    const float* __restrict__ W, int N, int K,
    float* __restrict__ C,
    const float* __restrict__ mu, const float* __restrict__ rstd,
    const float* __restrict__ lng, const float* __restrict__ lnb,
    const float* __restrict__ bias, const float* __restrict__ res, int ldres)
{
    __shared__ __align__(16) float As[16][132];
    __shared__ __align__(16) float Ws[16][132];
    int tid = threadIdx.x;
    int tx = tid & 15, ty = tid >> 4;
    int r0 = blockIdx.y * 128, n0 = blockIdx.x * 128;
    float acc[8][8];
#pragma unroll
    for (int i = 0; i < 8; i++) {
#pragma unroll
        for (int j = 0; j < 8; j++) acc[i][j] = 0.f;
    }
    for (int k0 = 0; k0 < K; k0 += 16) {
        // A tile: 128 rows x 16 cols, store transposed As[k][row]
#pragma unroll
        for (int q = 0; q < 2; q++) {
            int f4  = tid * 2 + q;
            int row = f4 >> 2, cc = (f4 & 3) * 4;
            float4 av = *(const float4*)&A[(size_t)(r0 + row) * lda + k0 + cc];
            if (LNA) {
                float m_ = mu[r0 + row], rv = rstd[r0 + row];
                float4 g4 = *(const float4*)&lng[k0 + cc];
                float4 b4 = *(const float4*)&lnb[k0 + cc];
                av.x = (av.x - m_) * rv * g4.x + b4.x;
                av.y = (av.y - m_) * rv * g4.y + b4.y;
                av.z = (av.z - m_) * rv * g4.z + b4.z;
                av.w = (av.w - m_) * rv * g4.w + b4.w;
            }
            As[cc + 0][row] = av.x;
            As[cc + 1][row] = av.y;
            As[cc + 2][row] = av.z;
            As[cc + 3][row] = av.w;
        }
        // W tile: 16 rows x 128 cols, direct
#pragma unroll
        for (int q = 0; q < 2; q++) {
            int f4 = tid * 2 + q;
            int kr = f4 >> 5, nc = (f4 & 31) * 4;
            *(float4*)&Ws[kr][nc] = *(const float4*)&W[(size_t)(k0 + kr) * N + n0 + nc];
        }
        __syncthreads();
#pragma unroll
        for (int kk = 0; kk < 16; kk++) {
            float a_[8], b_[8];
            *(float4*)&a_[0] = *(float4*)&As[kk][ty * 8];
            *(float4*)&a_[4] = *(float4*)&As[kk][ty * 8 + 4];
            *(float4*)&b_[0] = *(float4*)&Ws[kk][tx * 8];
            *(float4*)&b_[4] = *(float4*)&Ws[kk][tx * 8 + 4];
#pragma unroll
            for (int i = 0; i < 8; i++) {
#pragma unroll
                for (int j = 0; j < 8; j++)
                    acc[i][j] = fmaf(a_[i], b_[j], acc[i][j]);
            }
        }
        __syncthreads();
    }
#pragma unroll
    for (int i = 0; i < 8; i++) {
        int row = r0 + ty * 8 + i;
#pragma unroll
        for (int j4 = 0; j4 < 2; j4++) {
            int col = n0 + tx * 8 + j4 * 4;
            float4 o;
            o.x = acc[i][j4*4+0]; o.y = acc[i][j4*4+1];
            o.z = acc[i][j4*4+2]; o.w = acc[i][j4*4+3];
            if (EPI >= 1) {
                float4 bb = *(const float4*)&bias[col];
                o.x += bb.x; o.y += bb.y; o.z += bb.z; o.w += bb.w;
            }
            if (EPI == 2) {
                float4 rr = *(const float4*)&res[(size_t)row * ldres + col];
                o.x += rr.x; o.y += rr.y; o.z += rr.z; o.w += rr.w;
            }
            *(float4*)&C[(size_t)row * N + col] = o;
        }
    }
}

// ---------------- Depthwise causal conv (K=4) + bias + SiLU ----------------
// reads x_m = up[:, 0:1024] (stride 2048), writes c_act (stride 1024)
__global__ __launch_bounds__(256) void conv_k(const float* __restrict__ up,
                                              const float* __restrict__ w,
                                              const float* __restrict__ cb,
                                              float* __restrict__ cact) {
    int idx = blockIdx.x * 256 + threadIdx.x;
    int r = idx >> 8;
    int c = (idx & 255) * 4;
    int t = r & 1023;
    const float* base = up + (size_t)(r - t) * 2048;   // batch start row
    float4 acc = *(const float4*)&cb[c];
#pragma unroll
    for (int j = 0; j < 4; j++) {
        int tt = t - 3 + j;
        if (tt >= 0) {
            float4 xv = *(const float4*)&base[(size_t)tt * 2048 + c];
            float4 wv = *(const float4*)&w[j * I_DIM + c];
            acc.x = fmaf(xv.x, wv.x, acc.x);
            acc.y = fmaf(xv.y, wv.y, acc.y);
            acc.z = fmaf(xv.z, wv.z, acc.z);
            acc.w = fmaf(xv.w, wv.w, acc.w);
        }
    }
    acc.x = acc.x / (1.f + __expf(-acc.x));
    acc.y = acc.y / (1.f + __expf(-acc.y));
    acc.z = acc.z / (1.f + __expf(-acc.z));
    acc.w = acc.w / (1.f + __expf(-acc.w));
    *(float4*)&cact[(size_t)r * I_DIM + c] = acc;
}

// ---------------- i/f gate pre-activations ----------------
// ipre/fpre[b,h,s] = [q|k|v](row) . w_{i,f}[:,h] + b_{i,f}[h]   (3072-dot, H=4)
__global__ __launch_bounds__(256) void gates_k(const float* __restrict__ q,
                                               const float* __restrict__ k,
                                               const float* __restrict__ v,
                                               const float* __restrict__ wi,
                                               const float* __restrict__ bi,
                                               const float* __restrict__ wf,
                                               const float* __restrict__ bf,
                                               float* __restrict__ ipre,
                                               float* __restrict__ fpre) {
    int r = blockIdx.x;
    int tid = threadIdx.x;
    float ai[4] = {0,0,0,0}, af[4] = {0,0,0,0};
#pragma unroll
    for (int part = 0; part < 3; part++) {
        const float* src = (part == 0 ? q : (part == 1 ? k : v)) + (size_t)r * I_DIM;
        const float* wip = wi + part * I_DIM * 4;
        const float* wfp = wf + part * I_DIM * 4;
#pragma unroll
        for (int jj = 0; jj < 4; jj++) {
            int e = tid + jj * 256;
            float xv = src[e];
            float4 w4 = *(const float4*)&wip[e * 4];
            ai[0] = fmaf(xv, w4.x, ai[0]);
            ai[1] = fmaf(xv, w4.y, ai[1]);
            ai[2] = fmaf(xv, w4.z, ai[2]);
            ai[3] = fmaf(xv, w4.w, ai[3]);
            float4 f4v = *(const float4*)&wfp[e * 4];
            af[0] = fmaf(xv, f4v.x, af[0]);
            af[1] = fmaf(xv, f4v.y, af[1]);
            af[2] = fmaf(xv, f4v.z, af[2]);
            af[3] = fmaf(xv, f4v.w, af[3]);
        }
    }
#pragma unroll
    for (int off = 32; off > 0; off >>= 1) {
#pragma unroll
        for (int m = 0; m < 4; m++) {
            ai[m] += __shfl_down(ai[m], off);
            af[m] += __shfl_down(af[m], off);
        }
    }
    __shared__ float red[4][8];
    int wv_ = tid >> 6, lane = tid & 63;
    if (lane == 0) {
#pragma unroll
        for (int m = 0; m < 4; m++) { red[wv_][m] = ai[m]; red[wv_][4 + m] = af[m]; }
    }
    __syncthreads();
    if (tid < 8) {
        float s_ = red[0][tid] + red[1][tid] + red[2][tid] + red[3][tid];
        int b = r >> 10, ss = r & 1023;
        if (tid < 4) ipre[((size_t)(b * 4 + tid)) * 1024 + ss] = s_ + bi[tid];
        else         fpre[((size_t)(b * 4 + (tid - 4))) * 1024 + ss] = s_ + bf[tid - 4];
    }
}

// ---------------- per-(b,h) sequential scan ----------------
// lf=logsigmoid(fpre); lfc=cumsum(lf); c=ipre-lfc; M=cummax(c); nFl=exp(-(lfc+M))
__global__ void scan_k(const float* __restrict__ ipre, const float* __restrict__ fpre,
                       float* __restrict__ cArr, float* __restrict__ MArr,
                       float* __restrict__ nFl) {
    int tid = threadIdx.x;   // 0..31 == b*4+h
    size_t base = (size_t)tid * 1024;
    float lfc = 0.f, Mr = -1e30f;
    for (int s = 0; s < 1024; s++) {
        float fp = fpre[base + s];
        float lf = (fp >= 0.f) ? -log1pf(expf(-fp)) : (fp - log1pf(expf(fp)));
        lfc += lf;
        float c = ipre[base + s] - lfc;
        Mr = fmaxf(Mr, c);
        cArr[base + s] = c;
        MArr[base + s] = Mr;
        nFl[base + s]  = expf(-(lfc + Mr));
    }
}

// ---------------- fused causal mLSTM attention + groupnorm + gating ----------------
// grid (16, H, B), block 256. t-tile=64, s-tile=32.
// writes h_mod into up[:, 0:1024] (stride 2048) for the down GEMM.
__global__ __launch_bounds__(256) void attn_k(
    const float* __restrict__ qg, const float* __restrict__ kg, const float* __restrict__ vg,
    const float* __restrict__ cArr, const float* __restrict__ MArr, const float* __restrict__ nFl,
    const float* __restrict__ cact, float* up,
    const float* __restrict__ gng, const float* __restrict__ skip)
{
    __shared__ __align__(16) float qs[2176];   // [32][68]  (reused as gsum/gsq)
    __shared__ __align__(16) float ks[1152];   // [32][36]
    __shared__ __align__(16) float sc[2112];   // [64][33]
    __shared__ __align__(16) float vs[8320];   // [32][260]
    __shared__ float rs[64];
    __shared__ float gmu[64], gvr[64];

    int tid = threadIdx.x;
    int tx = tid & 15, ty = tid >> 4;
    int b = blockIdx.z, h = blockIdx.y;
    int T0 = blockIdx.x * 64;
    size_t base_bh = ((size_t)(b * H_NUM + h)) * S_LEN;
    size_t qoff = ((size_t)(b * S_LEN + T0)) * I_DIM + h * DH_;

    if (tid < 64) rs[tid] = 0.f;
    float acch[4][16];
#pragma unroll
    for (int i = 0; i < 4; i++) {
#pragma unroll
        for (int j = 0; j < 16; j++) acch[i][j] = 0.f;
    }

    int ntile = (T0 >> 5) + 2;
    for (int st = 0; st < ntile; st++) {
        int s0 = st * 32;
        float sacc[4][2] = {{0,0},{0,0},{0,0},{0,0}};
        // ---- scores: q(64x256) . k(32x256)^T in 8 dh-chunks ----
        for (int ch = 0; ch < 8; ch++) {
            int kk0 = ch * 32;
#pragma unroll
            for (int qq = 0; qq < 2; qq++) {
                int f4 = tid * 2 + qq;
                int tl = f4 >> 3, kq = (f4 & 7) * 4;
                float4 v4 = *(const float4*)&qg[qoff + (size_t)tl * I_DIM + kk0 + kq];
                qs[(kq + 0) * 68 + tl] = v4.x;
                qs[(kq + 1) * 68 + tl] = v4.y;
                qs[(kq + 2) * 68 + tl] = v4.z;
                qs[(kq + 3) * 68 + tl] = v4.w;
            }
            {
                int sl = tid >> 3, kq = (tid & 7) * 4;
                float4 v4 = *(const float4*)&kg[((size_t)(b * S_LEN + s0 + sl)) * I_DIM + h * DH_ + kk0 + kq];
                ks[(kq + 0) * 36 + sl] = v4.x;
                ks[(kq + 1) * 36 + sl] = v4.y;
                ks[(kq + 2) * 36 + sl] = v4.z;
                ks[(kq + 3) * 36 + sl] = v4.w;
            }
            __syncthreads();
#pragma unroll
            for (int kk = 0; kk < 32; kk++) {
                float4 a4 = *(const float4*)&qs[kk * 68 + ty * 4];
                float k0v = ks[kk * 36 + tx * 2];
                float k1v = ks[kk * 36 + tx * 2 + 1];
                sacc[0][0] = fmaf(a4.x, k0v, sacc[0][0]); sacc[0][1] = fmaf(a4.x, k1v, sacc[0][1]);
                sacc[1][0] = fmaf(a4.y, k0v, sacc[1][0]); sacc[1][1] = fmaf(a4.y, k1v, sacc[1][1]);
                sacc[2][0] = fmaf(a4.z, k0v, sacc[2][0]); sacc[2][1] = fmaf(a4.z, k1v, sacc[2][1]);
                sacc[3][0] = fmaf(a4.w, k0v, sacc[3][0]); sacc[3][1] = fmaf(a4.w, k1v, sacc[3][1]);
            }
            __syncthreads();
        }
        // ---- scale by DH^-0.5 * exp(c[s]-M[t]), causal mask, store to LDS ----
#pragma unroll
        for (int i = 0; i < 4; i++) {
            int t = T0 + ty * 4 + i;
            float Mv = MArr[base_bh + t];
#pragma unroll
            for (int j = 0; j < 2; j++) {
                int s = s0 + tx * 2 + j;
                float val = 0.f;
                if (s <= t) val = sacc[i][j] * 0.0625f * __expf(cArr[base_bh + s] - Mv);
                sc[(ty * 4 + i) * 33 + tx * 2 + j] = val;
            }
        }
        __syncthreads();
        // ---- rowsum accumulate + v tile load ----
        if (tid < 64) {
            float sum = 0.f;
#pragma unroll
            for (int ss = 0; ss < 32; ss++) sum += sc[tid * 33 + ss];
            rs[tid] += sum;
        }
#pragma unroll
        for (int w8 = 0; w8 < 8; w8++) {
            int f4 = tid + w8 * 256;
            int sl = f4 >> 6, dq = (f4 & 63) * 4;
            *(float4*)&vs[sl * 260 + dq] =
                *(const float4*)&vg[((size_t)(b * S_LEN + s0 + sl)) * I_DIM + h * DH_ + dq];
        }
        __syncthreads();
        // ---- PV: acch += sc @ v ----
        for (int s = 0; s < 32; s++) {
            float a0 = sc[(ty * 4 + 0) * 33 + s];
            float a1 = sc[(ty * 4 + 1) * 33 + s];
            float a2 = sc[(ty * 4 + 2) * 33 + s];
            float a3 = sc[(ty * 4 + 3) * 33 + s];
#pragma unroll
            for (int j = 0; j < 16; j++) {
                float vvv = vs[s * 260 + tx + 16 * j];
                acch[0][j] = fmaf(a0, vvv, acch[0][j]);
                acch[1][j] = fmaf(a1, vvv, acch[1][j]);
                acch[2][j] = fmaf(a2, vvv, acch[2][j]);
                acch[3][j] = fmaf(a3, vvv, acch[3][j]);
            }
        }
        __syncthreads();
    }
    // ---- normalize by n, groupnorm over DH, gn_g, +skip*c_act, *silu(z) ----
    float* gsum = qs;          // 64*17
    float* gsq  = qs + 1088;   // 64*17
#pragma unroll
    for (int i = 0; i < 4; i++) {
        int t = T0 + ty * 4 + i;
        float nt  = fmaxf(fabsf(rs[ty * 4 + i]), nFl[base_bh + t]);
        float inv = 1.f / nt;
        float ps = 0.f, pq = 0.f;
#pragma unroll
        for (int j = 0; j < 16; j++) {
            acch[i][j] *= inv;
            ps += acch[i][j];
            pq += acch[i][j] * acch[i][j];
        }
        gsum[(ty * 4 + i) * 17 + tx] = ps;
        gsq [(ty * 4 + i) * 17 + tx] = pq;
    }
    __syncthreads();
    if (tid < 64) {
        float s1 = 0.f, s2 = 0.f;
#pragma unroll
        for (int xx = 0; xx < 16; xx++) { s1 += gsum[tid * 17 + xx]; s2 += gsq[tid * 17 + xx]; }
        float mu_ = s1 * (1.f / 256.f);
        float var = s2 * (1.f / 256.f) - mu_ * mu_;
        gmu[tid] = mu_;
        gvr[tid] = rsqrtf(var + 1e-5f);
    }
    __syncthreads();
#pragma unroll
    for (int i = 0; i < 4; i++) {
        int t = T0 + ty * 4 + i;
        size_t r = (size_t)b * S_LEN + t;
        float mu_ = gmu[ty * 4 + i], rv = gvr[ty * 4 + i];
#pragma unroll
        for (int j = 0; j < 16; j++) {
            int cix = h * DH_ + tx + 16 * j;
            float val = (acch[i][j] - mu_) * rv * gng[cix];
            float ca  = cact[r * I_DIM + cix];
            float z   = up[r * 2048 + I_DIM + cix];
            float hm  = (val + skip[cix] * ca) * (z / (1.f + __expf(-z)));
            up[r * 2048 + cix] = hm;
        }
    }
}

// ---------------- host launch ----------------
extern "C" void kernel_launch(void* const* d_in, const int* in_sizes, int n_in,
                              void* d_out, int out_size, void* d_ws, size_t ws_size,
                              hipStream_t stream) {
    const float* x      = (const float*)d_in[0];
    const float* ln_g   = (const float*)d_in[1];
    const float* ln_b   = (const float*)d_in[2];
    const float* w_up   = (const float*)d_in[3];
    const float* conv_w = (const float*)d_in[4];
    const float* conv_b = (const float*)d_in[5];
    const float* wq     = (const float*)d_in[6];
    const float* wk     = (const float*)d_in[7];
    const float* wv     = (const float*)d_in[8];
    const float* w_i    = (const float*)d_in[9];
    const float* b_i    = (const float*)d_in[10];
    const float* w_f    = (const float*)d_in[11];
    const float* b_f    = (const float*)d_in[12];
    const float* skip   = (const float*)d_in[13];
    const float* gn_g   = (const float*)d_in[14];
    const float* w_down = (const float*)d_in[15];
    const float* b_down = (const float*)d_in[16];
    const float* w_fin  = (const float*)d_in[17];
    const float* b_fin  = (const float*)d_in[18];

    float* ws   = (float*)d_ws;
    float* up   = ws;                                  // 8192*2048
    float* cact = up   + (size_t)ROWS * 2048;          // 8192*1024
    float* qb   = cact + (size_t)ROWS * 1024;          // 8192*1024
    float* kb   = qb   + (size_t)ROWS * 1024;          // 8192*1024
    float* vb   = kb   + (size_t)ROWS * 1024;          // 8192*1024
    float* xa   = vb   + (size_t)ROWS * 1024;          // 8192*512
    float* xb2  = xa   + (size_t)ROWS * 512;           // 8192*512
    float* muA  = xb2  + (size_t)ROWS * 512;           // 8192
    float* rstdA= muA  + ROWS;                         // 8192
    float* ipre = rstdA + ROWS;                        // 32768
    float* fpre = ipre + 32768;
    float* cA   = fpre + 32768;
    float* MA   = cA   + 32768;
    float* nF   = MA   + 32768;

    const float* xin = x;
    for (int l = 0; l < 2; l++) {
        float* xout = (l == 0) ? xa : xb2;
        ln_stats_k<<<ROWS / 4, 256, 0, stream>>>(xin, muA, rstdA);
        gemm_k<1, 0><<<dim3(16, 64), 256, 0, stream>>>(
            xin, E_DIM, w_up + (size_t)l * E_DIM * 2048, 2048, E_DIM, up,
            muA, rstdA, ln_g + l * E_DIM, ln_b + l * E_DIM, nullptr, nullptr, 0);
        conv_k<<<8192, 256, 0, stream>>>(up, conv_w + l * 4 * I_DIM, conv_b + l * I_DIM, cact);
        gemm_k<0, 0><<<dim3(8, 64), 256, 0, stream>>>(
            up, 2048, wv + (size_t)l * I_DIM * I_DIM, I_DIM, I_DIM, vb,
            nullptr, nullptr, nullptr, nullptr, nullptr, nullptr, 0);
        gemm_k<0, 0><<<dim3(8, 64), 256, 0, stream>>>(
            cact, I_DIM, wq + (size_t)l * I_DIM * I_DIM, I_DIM, I_DIM, qb,
            nullptr, nullptr, nullptr, nullptr, nullptr, nullptr, 0);
        gemm_k<0, 0><<<dim3(8, 64), 256, 0, stream>>>(
            cact, I_DIM, wk + (size_t)l * I_DIM * I_DIM, I_DIM, I_DIM, kb,
            nullptr, nullptr, nullptr, nullptr, nullptr, nullptr, 0);
        gates_k<<<ROWS, 256, 0, stream>>>(qb, kb, vb,
            w_i + l * 3072 * 4, b_i + l * 4, w_f + l * 3072 * 4, b_f + l * 4, ipre, fpre);
        scan_k<<<1, 32, 0, stream>>>(ipre, fpre, cA, MA, nF);
        attn_k<<<dim3(16, 4, 8), 256, 0, stream>>>(qb, kb, vb, cA, MA, nF, cact, up,
            gn_g + l * I_DIM, skip + l * I_DIM);
        gemm_k<0, 2><<<dim3(4, 64), 256, 0, stream>>>(
            up, 2048, w_down + (size_t)l * I_DIM * E_DIM, E_DIM, I_DIM, xout,
            nullptr, nullptr, nullptr, nullptr, b_down + l * E_DIM, xin, E_DIM);
        xin = xout;
    }
    gemm_k<0, 1><<<dim3(1, 64), 256, 0, stream>>>(
        xin, E_DIM, w_fin, 128, E_DIM, (float*)d_out,
        nullptr, nullptr, nullptr, nullptr, b_fin, nullptr, 0);
}

// Round 2
// 1977.399 us; speedup vs baseline: 2.5266x; 2.5266x over previous
//
#include <hip/hip_runtime.h>
#include <math.h>

#define S_LEN 1024
#define I_DIM 1024
#define DH_   256
#define H_NUM 4
#define B_NUM 8
#define ROWS  (B_NUM*S_LEN)   // 8192

#define GLOBAL_AS __attribute__((address_space(1)))
#define LDS_AS    __attribute__((address_space(3)))

typedef __attribute__((ext_vector_type(8))) short bf16x8;
typedef __attribute__((ext_vector_type(4))) float f32x4;
typedef unsigned short u16;

__device__ __forceinline__ u16 f2bf(float f) {
    union { float f; unsigned u; } v; v.f = f;
    unsigned r = v.u + 0x7FFF + ((v.u >> 16) & 1);
    return (u16)(r >> 16);
}
__device__ __forceinline__ float bf2f(u16 h) {
    union { unsigned u; float f; } v; v.u = ((unsigned)h) << 16;
    return v.f;
}

// ---------------- fused LayerNorm -> bf16 ----------------
__global__ __launch_bounds__(64) void ln_fused_k(const float* __restrict__ x,
                                                 const float* __restrict__ g,
                                                 const float* __restrict__ b,
                                                 u16* __restrict__ out) {
    int row = blockIdx.x, lane = threadIdx.x;
    const float* xr = x + (size_t)row * 512;
    float4 a = *(const float4*)&xr[lane * 8];
    float4 c = *(const float4*)&xr[lane * 8 + 4];
    float s  = a.x + a.y + a.z + a.w + c.x + c.y + c.z + c.w;
    float s2 = a.x*a.x + a.y*a.y + a.z*a.z + a.w*a.w
             + c.x*c.x + c.y*c.y + c.z*c.z + c.w*c.w;
#pragma unroll
    for (int off = 32; off > 0; off >>= 1) {
        s  += __shfl_down(s, off);
        s2 += __shfl_down(s2, off);
    }
    s = __shfl(s, 0); s2 = __shfl(s2, 0);
    float mu = s * (1.f / 512.f);
    float rstd = rsqrtf(s2 * (1.f / 512.f) - mu * mu + 1e-5f);
    int e0 = lane * 8;
    float y[8] = {a.x,a.y,a.z,a.w,c.x,c.y,c.z,c.w};
    ushort4 o0, o1;
    o0.x = f2bf((y[0]-mu)*rstd*g[e0+0]+b[e0+0]);
    o0.y = f2bf((y[1]-mu)*rstd*g[e0+1]+b[e0+1]);
    o0.z = f2bf((y[2]-mu)*rstd*g[e0+2]+b[e0+2]);
    o0.w = f2bf((y[3]-mu)*rstd*g[e0+3]+b[e0+3]);
    o1.x = f2bf((y[4]-mu)*rstd*g[e0+4]+b[e0+4]);
    o1.y = f2bf((y[5]-mu)*rstd*g[e0+5]+b[e0+5]);
    o1.z = f2bf((y[6]-mu)*rstd*g[e0+6]+b[e0+6]);
    o1.w = f2bf((y[7]-mu)*rstd*g[e0+7]+b[e0+7]);
    *(ushort4*)&out[(size_t)row * 512 + e0]     = o0;
    *(ushort4*)&out[(size_t)row * 512 + e0 + 4] = o1;
}

// ---------------- weight transpose + cvt: Wt[n][k] = bf16(W[k][n]) ----------------
__global__ __launch_bounds__(256) void cvtT_k(const float* __restrict__ W,
                                              u16* __restrict__ Wt, int K, int N) {
    __shared__ float t[32][33];
    int k0 = blockIdx.x * 32, n0 = blockIdx.y * 32;
    int c = threadIdx.x & 31, r8 = threadIdx.x >> 5;
#pragma unroll
    for (int q = 0; q < 4; q++) {
        int r = r8 * 4 + q;
        t[r][c] = W[(size_t)(k0 + r) * N + n0 + c];
    }
    __syncthreads();
#pragma unroll
    for (int q = 0; q < 4; q++) {
        int r = r8 * 4 + q;
        Wt[(size_t)(n0 + r) * K + k0 + c] = f2bf(t[c][r]);
    }
}

// ---------------- bf16 MFMA GEMM: C[8192 x N] = A[8192 x K] @ Wt[N x K]^T ----------------
// EPI 0: bf16 out only. 1: up (col<1024 -> bf16 xm, else fp32 z). 2: +bias+res, fp32+bf16.
// 3: +bias, fp32 out.
template<int EPI>
__global__ __launch_bounds__(256) void gemm_bf16_k(
    const u16* __restrict__ A, const u16* __restrict__ Wt, int N, int K,
    float* __restrict__ Cf, u16* __restrict__ Cb,
    const float* __restrict__ bias, const float* __restrict__ res, int ldres)
{
    __shared__ __align__(16) u16 As[128 * 32];
    __shared__ __align__(16) u16 Bs[128 * 32];
    int tid = threadIdx.x;
    int lane = tid & 63;
    int wm = (tid >> 6) & 1, wn = tid >> 7;
    int r0 = blockIdx.y * 128, n0 = blockIdx.x * 128;
    int arow = tid >> 2, acol = (tid & 3) * 8;
    const u16* ap0 = A  + (size_t)(r0 + arow) * K + acol;
    const u16* ap1 = A  + (size_t)(r0 + 64 + arow) * K + acol;
    const u16* bp0 = Wt + (size_t)(n0 + arow) * K + acol;
    const u16* bp1 = Wt + (size_t)(n0 + 64 + arow) * K + acol;
    u16* al0 = As + tid * 8;
    u16* al1 = As + 2048 + tid * 8;
    u16* bl0 = Bs + tid * 8;
    u16* bl1 = Bs + 2048 + tid * 8;

    f32x4 acc[4][4];
#pragma unroll
    for (int i = 0; i < 4; i++)
#pragma unroll
        for (int j = 0; j < 4; j++) acc[i][j] = (f32x4){0.f, 0.f, 0.f, 0.f};

    int lm = lane & 15, lk = (lane >> 4) * 8;
    for (int k0 = 0; k0 < K; k0 += 32) {
        __builtin_amdgcn_global_load_lds((const GLOBAL_AS unsigned int*)(ap0 + k0), (LDS_AS unsigned int*)al0, 16, 0, 0);
        __builtin_amdgcn_global_load_lds((const GLOBAL_AS unsigned int*)(ap1 + k0), (LDS_AS unsigned int*)al1, 16, 0, 0);
        __builtin_amdgcn_global_load_lds((const GLOBAL_AS unsigned int*)(bp0 + k0), (LDS_AS unsigned int*)bl0, 16, 0, 0);
        __builtin_amdgcn_global_load_lds((const GLOBAL_AS unsigned int*)(bp1 + k0), (LDS_AS unsigned int*)bl1, 16, 0, 0);
        __syncthreads();
        bf16x8 af[4], bfr[4];
#pragma unroll
        for (int f = 0; f < 4; f++) {
            af[f]  = *(const bf16x8*)&As[(wm * 64 + f * 16 + lm) * 32 + lk];
            bfr[f] = *(const bf16x8*)&Bs[(wn * 64 + f * 16 + lm) * 32 + lk];
        }
#pragma unroll
        for (int i = 0; i < 4; i++)
#pragma unroll
            for (int j = 0; j < 4; j++)
                acc[i][j] = __builtin_amdgcn_mfma_f32_16x16x32_bf16(af[i], bfr[j], acc[i][j], 0, 0, 0);
        __syncthreads();
    }
    int lr = (lane >> 4) * 4;
#pragma unroll
    for (int i = 0; i < 4; i++) {
#pragma unroll
        for (int j = 0; j < 4; j++) {
#pragma unroll
            for (int q = 0; q < 4; q++) {
                int row = r0 + wm * 64 + i * 16 + lr + q;
                int col = n0 + wn * 64 + j * 16 + lm;
                float o = acc[i][j][q];
                if (EPI == 0) {
                    Cb[(size_t)row * N + col] = f2bf(o);
                } else if (EPI == 1) {
                    if (col < 1024) Cb[(size_t)row * 1024 + col] = f2bf(o);
                    else            Cf[(size_t)row * 1024 + (col - 1024)] = o;
                } else if (EPI == 2) {
                    o += bias[col] + res[(size_t)row * ldres + col];
                    Cf[(size_t)row * N + col] = o;
                    Cb[(size_t)row * N + col] = f2bf(o);
                } else {
                    o += bias[col];
                    Cf[(size_t)row * N + col] = o;
                }
            }
        }
    }
}

// ---------------- depthwise causal conv (K=4) + bias + SiLU, bf16 in/out ----------------
__global__ __launch_bounds__(256) void conv_k(const u16* __restrict__ xm,
                                              const float* __restrict__ w,
                                              const float* __restrict__ cb,
                                              u16* __restrict__ cact) {
    int idx = blockIdx.x * 256 + threadIdx.x;
    int r = idx >> 8;
    int c = (idx & 255) * 4;
    int t = r & 1023;
    const u16* base = xm + (size_t)(r - t) * I_DIM;
    float4 acc = *(const float4*)&cb[c];
#pragma unroll
    for (int j = 0; j < 4; j++) {
        int tt = t - 3 + j;
        if (tt >= 0) {
            short4 s = *(const short4*)&base[(size_t)tt * I_DIM + c];
            float4 wv = *(const float4*)&w[j * I_DIM + c];
            acc.x = fmaf(bf2f((u16)s.x), wv.x, acc.x);
            acc.y = fmaf(bf2f((u16)s.y), wv.y, acc.y);
            acc.z = fmaf(bf2f((u16)s.z), wv.z, acc.z);
            acc.w = fmaf(bf2f((u16)s.w), wv.w, acc.w);
        }
    }
    acc.x = acc.x / (1.f + __expf(-acc.x));
    acc.y = acc.y / (1.f + __expf(-acc.y));
    acc.z = acc.z / (1.f + __expf(-acc.z));
    acc.w = acc.w / (1.f + __expf(-acc.w));
    ushort4 o;
    o.x = f2bf(acc.x); o.y = f2bf(acc.y); o.z = f2bf(acc.z); o.w = f2bf(acc.w);
    *(ushort4*)&cact[(size_t)r * I_DIM + c] = o;
}

// ---------------- i/f gate pre-activations (bf16 qkv inputs) ----------------
__global__ __launch_bounds__(256) void gates_k(const u16* __restrict__ q,
                                               const u16* __restrict__ k,
                                               const u16* __restrict__ v,
                                               const float* __restrict__ wi,
                                               const float* __restrict__ bi,
                                               const float* __restrict__ wf,
                                               const float* __restrict__ bf,
                                               float* __restrict__ ipre,
                                               float* __restrict__ fpre) {
    int r = blockIdx.x;
    int tid = threadIdx.x;
    float ai[4] = {0,0,0,0}, af[4] = {0,0,0,0};
#pragma unroll
    for (int part = 0; part < 3; part++) {
        const u16* src = (part == 0 ? q : (part == 1 ? k : v)) + (size_t)r * I_DIM;
        const float* wip = wi + part * I_DIM * 4;
        const float* wfp = wf + part * I_DIM * 4;
#pragma unroll
        for (int jj = 0; jj < 4; jj++) {
            int e = tid + jj * 256;
            float xv = bf2f(src[e]);
            float4 w4 = *(const float4*)&wip[e * 4];
            ai[0] = fmaf(xv, w4.x, ai[0]);
            ai[1] = fmaf(xv, w4.y, ai[1]);
            ai[2] = fmaf(xv, w4.z, ai[2]);
            ai[3] = fmaf(xv, w4.w, ai[3]);
            float4 f4v = *(const float4*)&wfp[e * 4];
            af[0] = fmaf(xv, f4v.x, af[0]);
            af[1] = fmaf(xv, f4v.y, af[1]);
            af[2] = fmaf(xv, f4v.z, af[2]);
            af[3] = fmaf(xv, f4v.w, af[3]);
        }
    }
#pragma unroll
    for (int off = 32; off > 0; off >>= 1) {
#pragma unroll
        for (int m = 0; m < 4; m++) {
            ai[m] += __shfl_down(ai[m], off);
            af[m] += __shfl_down(af[m], off);
        }
    }
    __shared__ float red[4][8];
    int wv_ = tid >> 6, lane = tid & 63;
    if (lane == 0) {
#pragma unroll
        for (int m = 0; m < 4; m++) { red[wv_][m] = ai[m]; red[wv_][4 + m] = af[m]; }
    }
    __syncthreads();
    if (tid < 8) {
        float s_ = red[0][tid] + red[1][tid] + red[2][tid] + red[3][tid];
        int b = r >> 10, ss = r & 1023;
        if (tid < 4) ipre[((size_t)(b * 4 + tid)) * 1024 + ss] = s_ + bi[tid];
        else         fpre[((size_t)(b * 4 + (tid - 4))) * 1024 + ss] = s_ + bf[tid - 4];
    }
}

// ---------------- parallel scan per (b,h): cumsum(logsigmoid) + cummax ----------------
__global__ __launch_bounds__(1024) void scan_k(const float* __restrict__ ipre,
                                               const float* __restrict__ fpre,
                                               float* __restrict__ cA,
                                               float* __restrict__ MA,
                                               float* __restrict__ nF) {
    __shared__ float buf[1024];
    int bh = blockIdx.x, t = threadIdx.x;
    size_t base = (size_t)bh * 1024;
    float fp = fpre[base + t];
    float lf = (fp >= 0.f) ? -log1pf(expf(-fp)) : (fp - log1pf(expf(fp)));
    buf[t] = lf; __syncthreads();
    for (int off = 1; off < 1024; off <<= 1) {
        float u = (t >= off) ? buf[t - off] : 0.f;
        __syncthreads();
        buf[t] += u;
        __syncthreads();
    }
    float lfc = buf[t];
    float c = ipre[base + t] - lfc;
    __syncthreads();
    buf[t] = c; __syncthreads();
    for (int off = 1; off < 1024; off <<= 1) {
        float u = (t >= off) ? buf[t - off] : -3.4e38f;
        __syncthreads();
        buf[t] = fmaxf(buf[t], u);
        __syncthreads();
    }
    float M = buf[t];
    cA[base + t] = c;
    MA[base + t] = M;
    nF[base + t] = expf(-(lfc + M));
}

// ---------------- fused causal mLSTM attention + groupnorm + gating (bf16 inputs) ----------------
__global__ __launch_bounds__(256) void attn_k(
    const u16* __restrict__ qg, const u16* __restrict__ kg, const u16* __restrict__ vg,
    const float* __restrict__ cArr, const float* __restrict__ MArr, const float* __restrict__ nFl,
    const u16* __restrict__ cact, const float* __restrict__ zb, u16* __restrict__ hb,
    const float* __restrict__ gng, const float* __restrict__ skip)
{
    __shared__ __align__(16) float qs[2176];   // [32][68] (reused as gsum/gsq)
    __shared__ __align__(16) float ks[1152];   // [32][36]
    __shared__ __align__(16) float sc[2112];   // [64][33]
    __shared__ __align__(16) float vs[8320];   // [32][260]
    __shared__ float rs[64];
    __shared__ float gmu[64], gvr[64];

    int tid = threadIdx.x;
    int tx = tid & 15, ty = tid >> 4;
    int b = blockIdx.z, h = blockIdx.y;
    int T0 = blockIdx.x * 64;
    size_t base_bh = ((size_t)(b * H_NUM + h)) * S_LEN;
    size_t qoff = ((size_t)(b * S_LEN + T0)) * I_DIM + h * DH_;

    if (tid < 64) rs[tid] = 0.f;
    float acch[4][16];
#pragma unroll
    for (int i = 0; i < 4; i++)
#pragma unroll
        for (int j = 0; j < 16; j++) acch[i][j] = 0.f;

    int ntile = (T0 >> 5) + 2;
    for (int st = 0; st < ntile; st++) {
        int s0 = st * 32;
        float sacc[4][2] = {{0,0},{0,0},{0,0},{0,0}};
        for (int ch = 0; ch < 8; ch++) {
            int kk0 = ch * 32;
#pragma unroll
            for (int qq = 0; qq < 2; qq++) {
                int f4 = tid * 2 + qq;
                int tl = f4 >> 3, kq = (f4 & 7) * 4;
                short4 s4 = *(const short4*)&qg[qoff + (size_t)tl * I_DIM + kk0 + kq];
                qs[(kq + 0) * 68 + tl] = bf2f((u16)s4.x);
                qs[(kq + 1) * 68 + tl] = bf2f((u16)s4.y);
                qs[(kq + 2) * 68 + tl] = bf2f((u16)s4.z);
                qs[(kq + 3) * 68 + tl] = bf2f((u16)s4.w);
            }
            {
                int sl = tid >> 3, kq = (tid & 7) * 4;
                short4 s4 = *(const short4*)&kg[((size_t)(b * S_LEN + s0 + sl)) * I_DIM + h * DH_ + kk0 + kq];
                ks[(kq + 0) * 36 + sl] = bf2f((u16)s4.x);
                ks[(kq + 1) * 36 + sl] = bf2f((u16)s4.y);
                ks[(kq + 2) * 36 + sl] = bf2f((u16)s4.z);
                ks[(kq + 3) * 36 + sl] = bf2f((u16)s4.w);
            }
            __syncthreads();
#pragma unroll
            for (int kk = 0; kk < 32; kk++) {
                float4 a4 = *(const float4*)&qs[kk * 68 + ty * 4];
                float k0v = ks[kk * 36 + tx * 2];
                float k1v = ks[kk * 36 + tx * 2 + 1];
                sacc[0][0] = fmaf(a4.x, k0v, sacc[0][0]); sacc[0][1] = fmaf(a4.x, k1v, sacc[0][1]);
                sacc[1][0] = fmaf(a4.y, k0v, sacc[1][0]); sacc[1][1] = fmaf(a4.y, k1v, sacc[1][1]);
                sacc[2][0] = fmaf(a4.z, k0v, sacc[2][0]); sacc[2][1] = fmaf(a4.z, k1v, sacc[2][1]);
                sacc[3][0] = fmaf(a4.w, k0v, sacc[3][0]); sacc[3][1] = fmaf(a4.w, k1v, sacc[3][1]);
            }
            __syncthreads();
        }
#pragma unroll
        for (int i = 0; i < 4; i++) {
            int t = T0 + ty * 4 + i;
            float Mv = MArr[base_bh + t];
#pragma unroll
            for (int j = 0; j < 2; j++) {
                int s = s0 + tx * 2 + j;
                float val = 0.f;
                if (s <= t) val = sacc[i][j] * 0.0625f * __expf(cArr[base_bh + s] - Mv);
                sc[(ty * 4 + i) * 33 + tx * 2 + j] = val;
            }
        }
        __syncthreads();
        if (tid < 64) {
            float sum = 0.f;
#pragma unroll
            for (int ss = 0; ss < 32; ss++) sum += sc[tid * 33 + ss];
            rs[tid] += sum;
        }
#pragma unroll
        for (int w8 = 0; w8 < 8; w8++) {
            int f4 = tid + w8 * 256;
            int sl = f4 >> 6, dq = (f4 & 63) * 4;
            short4 s4 = *(const short4*)&vg[((size_t)(b * S_LEN + s0 + sl)) * I_DIM + h * DH_ + dq];
            float4 vv;
            vv.x = bf2f((u16)s4.x); vv.y = bf2f((u16)s4.y);
            vv.z = bf2f((u16)s4.z); vv.w = bf2f((u16)s4.w);
            *(float4*)&vs[sl * 260 + dq] = vv;
        }
        __syncthreads();
        for (int s = 0; s < 32; s++) {
            float a0 = sc[(ty * 4 + 0) * 33 + s];
            float a1 = sc[(ty * 4 + 1) * 33 + s];
            float a2 = sc[(ty * 4 + 2) * 33 + s];
            float a3 = sc[(ty * 4 + 3) * 33 + s];
#pragma unroll
            for (int j = 0; j < 16; j++) {
                float vvv = vs[s * 260 + tx + 16 * j];
                acch[0][j] = fmaf(a0, vvv, acch[0][j]);
                acch[1][j] = fmaf(a1, vvv, acch[1][j]);
                acch[2][j] = fmaf(a2, vvv, acch[2][j]);
                acch[3][j] = fmaf(a3, vvv, acch[3][j]);
            }
        }
        __syncthreads();
    }
    float* gsum = qs;
    float* gsq  = qs + 1088;
#pragma unroll
    for (int i = 0; i < 4; i++) {
        int t = T0 + ty * 4 + i;
        float nt  = fmaxf(fabsf(rs[ty * 4 + i]), nFl[base_bh + t]);
        float inv = 1.f / nt;
        float ps = 0.f, pq = 0.f;
#pragma unroll
        for (int j = 0; j < 16; j++) {
            acch[i][j] *= inv;
            ps += acch[i][j];
            pq += acch[i][j] * acch[i][j];
        }
        gsum[(ty * 4 + i) * 17 + tx] = ps;
        gsq [(ty * 4 + i) * 17 + tx] = pq;
    }
    __syncthreads();
    if (tid < 64) {
        float s1 = 0.f, s2 = 0.f;
#pragma unroll
        for (int xx = 0; xx < 16; xx++) { s1 += gsum[tid * 17 + xx]; s2 += gsq[tid * 17 + xx]; }
        float mu_ = s1 * (1.f / 256.f);
        float var = s2 * (1.f / 256.f) - mu_ * mu_;
        gmu[tid] = mu_;
        gvr[tid] = rsqrtf(var + 1e-5f);
    }
    __syncthreads();
#pragma unroll
    for (int i = 0; i < 4; i++) {
        int t = T0 + ty * 4 + i;
        size_t r = (size_t)b * S_LEN + t;
        float mu_ = gmu[ty * 4 + i], rv = gvr[ty * 4 + i];
#pragma unroll
        for (int j = 0; j < 16; j++) {
            int cix = h * DH_ + tx + 16 * j;
            float val = (acch[i][j] - mu_) * rv * gng[cix];
            float ca  = bf2f(cact[r * I_DIM + cix]);
            float z   = zb[r * I_DIM + cix];
            float hm  = (val + skip[cix] * ca) * (z / (1.f + __expf(-z)));
            hb[r * I_DIM + cix] = f2bf(hm);
        }
    }
}

// ---------------- host launch ----------------
extern "C" void kernel_launch(void* const* d_in, const int* in_sizes, int n_in,
                              void* d_out, int out_size, void* d_ws, size_t ws_size,
                              hipStream_t stream) {
    const float* x      = (const float*)d_in[0];
    const float* ln_g   = (const float*)d_in[1];
    const float* ln_b   = (const float*)d_in[2];
    const float* w_up   = (const float*)d_in[3];
    const float* conv_w = (const float*)d_in[4];
    const float* conv_b = (const float*)d_in[5];
    const float* wq     = (const float*)d_in[6];
    const float* wk     = (const float*)d_in[7];
    const float* wv     = (const float*)d_in[8];
    const float* w_i    = (const float*)d_in[9];
    const float* b_i    = (const float*)d_in[10];
    const float* w_f    = (const float*)d_in[11];
    const float* b_f    = (const float*)d_in[12];
    const float* skip   = (const float*)d_in[13];
    const float* gn_g   = (const float*)d_in[14];
    const float* w_down = (const float*)d_in[15];
    const float* b_down = (const float*)d_in[16];
    const float* w_fin  = (const float*)d_in[17];
    const float* b_fin  = (const float*)d_in[18];

    char* p = (char*)d_ws;
    auto alloc = [&](size_t bytes) { void* r = p; p += (bytes + 255) & ~(size_t)255; return r; };
    float* zbuf  = (float*)alloc((size_t)ROWS * 1024 * 4);
    float* xa    = (float*)alloc((size_t)ROWS * 512 * 4);
    float* xb2   = (float*)alloc((size_t)ROWS * 512 * 4);
    u16*  xln    = (u16*)alloc((size_t)ROWS * 512 * 2);
    u16*  xm     = (u16*)alloc((size_t)ROWS * 1024 * 2);
    u16*  cactb  = (u16*)alloc((size_t)ROWS * 1024 * 2);
    u16*  qbf    = (u16*)alloc((size_t)ROWS * 1024 * 2);
    u16*  kbf    = (u16*)alloc((size_t)ROWS * 1024 * 2);
    u16*  vbf    = (u16*)alloc((size_t)ROWS * 1024 * 2);
    u16*  hbf    = (u16*)alloc((size_t)ROWS * 1024 * 2);
    u16*  xoutb  = (u16*)alloc((size_t)ROWS * 512 * 2);
    u16*  wupT   = (u16*)alloc((size_t)2 * 2048 * 512 * 2);
    u16*  wqT    = (u16*)alloc((size_t)2 * 1024 * 1024 * 2);
    u16*  wkT    = (u16*)alloc((size_t)2 * 1024 * 1024 * 2);
    u16*  wvT    = (u16*)alloc((size_t)2 * 1024 * 1024 * 2);
    u16*  wdT    = (u16*)alloc((size_t)2 * 512 * 1024 * 2);
    u16*  wfT    = (u16*)alloc((size_t)128 * 512 * 2);
    float* ipre  = (float*)alloc(32768 * 4);
    float* fpre  = (float*)alloc(32768 * 4);
    float* cA    = (float*)alloc(32768 * 4);
    float* MA    = (float*)alloc(32768 * 4);
    float* nF    = (float*)alloc(32768 * 4);

    // weight conversions (transpose to [N][K] bf16)
    for (int l = 0; l < 2; l++) {
        cvtT_k<<<dim3(16, 64), 256, 0, stream>>>(w_up + (size_t)l * 512 * 2048, wupT + (size_t)l * 2048 * 512, 512, 2048);
        cvtT_k<<<dim3(32, 32), 256, 0, stream>>>(wq + (size_t)l * 1024 * 1024, wqT + (size_t)l * 1024 * 1024, 1024, 1024);
        cvtT_k<<<dim3(32, 32), 256, 0, stream>>>(wk + (size_t)l * 1024 * 1024, wkT + (size_t)l * 1024 * 1024, 1024, 1024);
        cvtT_k<<<dim3(32, 32), 256, 0, stream>>>(wv + (size_t)l * 1024 * 1024, wvT + (size_t)l * 1024 * 1024, 1024, 1024);
        cvtT_k<<<dim3(32, 16), 256, 0, stream>>>(w_down + (size_t)l * 1024 * 512, wdT + (size_t)l * 512 * 1024, 1024, 512);
    }
    cvtT_k<<<dim3(16, 4), 256, 0, stream>>>(w_fin, wfT, 512, 128);

    const float* xin = x;
    for (int l = 0; l < 2; l++) {
        float* xout = (l == 0) ? xa : xb2;
        ln_fused_k<<<ROWS, 64, 0, stream>>>(xin, ln_g + l * 512, ln_b + l * 512, xln);
        gemm_bf16_k<1><<<dim3(16, 64), 256, 0, stream>>>(
            xln, wupT + (size_t)l * 2048 * 512, 2048, 512, zbuf, xm, nullptr, nullptr, 0);
        conv_k<<<ROWS, 256, 0, stream>>>(xm, conv_w + l * 4 * I_DIM, conv_b + l * I_DIM, cactb);
        gemm_bf16_k<0><<<dim3(8, 64), 256, 0, stream>>>(
            xm, wvT + (size_t)l * 1024 * 1024, 1024, 1024, nullptr, vbf, nullptr, nullptr, 0);
        gemm_bf16_k<0><<<dim3(8, 64), 256, 0, stream>>>(
            cactb, wqT + (size_t)l * 1024 * 1024, 1024, 1024, nullptr, qbf, nullptr, nullptr, 0);
        gemm_bf16_k<0><<<dim3(8, 64), 256, 0, stream>>>(
            cactb, wkT + (size_t)l * 1024 * 1024, 1024, 1024, nullptr, kbf, nullptr, nullptr, 0);
        gates_k<<<ROWS, 256, 0, stream>>>(qbf, kbf, vbf,
            w_i + l * 3072 * 4, b_i + l * 4, w_f + l * 3072 * 4, b_f + l * 4, ipre, fpre);
        scan_k<<<32, 1024, 0, stream>>>(ipre, fpre, cA, MA, nF);
        attn_k<<<dim3(16, 4, 8), 256, 0, stream>>>(qbf, kbf, vbf, cA, MA, nF, cactb, zbuf, hbf,
            gn_g + l * I_DIM, skip + l * I_DIM);
        gemm_bf16_k<2><<<dim3(4, 64), 256, 0, stream>>>(
            hbf, wdT + (size_t)l * 512 * 1024, 512, 1024, xout, xoutb,
            b_down + l * 512, xin, 512);
        xin = xout;
    }
    gemm_bf16_k<3><<<dim3(1, 64), 256, 0, stream>>>(
        xoutb, wfT, 128, 512, (float*)d_out, nullptr, b_fin, nullptr, 0);
}

// Round 3
// 1032.196 us; speedup vs baseline: 4.8403x; 1.9157x over previous
//
#include <hip/hip_runtime.h>
#include <math.h>

#define S_LEN 1024
#define I_DIM 1024
#define DH_   256
#define H_NUM 4
#define B_NUM 8
#define ROWS  (B_NUM*S_LEN)   // 8192

#define GLOBAL_AS __attribute__((address_space(1)))
#define LDS_AS    __attribute__((address_space(3)))

typedef __attribute__((ext_vector_type(8))) short bf16x8;
typedef __attribute__((ext_vector_type(4))) float f32x4;
typedef unsigned short u16;

__device__ __forceinline__ u16 f2bf(float f) {
    union { float f; unsigned u; } v; v.f = f;
    unsigned r = v.u + 0x7FFF + ((v.u >> 16) & 1);
    return (u16)(r >> 16);
}
__device__ __forceinline__ float bf2f(u16 h) {
    union { unsigned u; float f; } v; v.u = ((unsigned)h) << 16;
    return v.f;
}

// ---------------- fused LayerNorm -> bf16 ----------------
__global__ __launch_bounds__(64) void ln_fused_k(const float* __restrict__ x,
                                                 const float* __restrict__ g,
                                                 const float* __restrict__ b,
                                                 u16* __restrict__ out) {
    int row = blockIdx.x, lane = threadIdx.x;
    const float* xr = x + (size_t)row * 512;
    float4 a = *(const float4*)&xr[lane * 8];
    float4 c = *(const float4*)&xr[lane * 8 + 4];
    float s  = a.x + a.y + a.z + a.w + c.x + c.y + c.z + c.w;
    float s2 = a.x*a.x + a.y*a.y + a.z*a.z + a.w*a.w
             + c.x*c.x + c.y*c.y + c.z*c.z + c.w*c.w;
#pragma unroll
    for (int off = 32; off > 0; off >>= 1) {
        s  += __shfl_down(s, off);
        s2 += __shfl_down(s2, off);
    }
    s = __shfl(s, 0); s2 = __shfl(s2, 0);
    float mu = s * (1.f / 512.f);
    float rstd = rsqrtf(s2 * (1.f / 512.f) - mu * mu + 1e-5f);
    int e0 = lane * 8;
    float y[8] = {a.x,a.y,a.z,a.w,c.x,c.y,c.z,c.w};
    ushort4 o0, o1;
    o0.x = f2bf((y[0]-mu)*rstd*g[e0+0]+b[e0+0]);
    o0.y = f2bf((y[1]-mu)*rstd*g[e0+1]+b[e0+1]);
    o0.z = f2bf((y[2]-mu)*rstd*g[e0+2]+b[e0+2]);
    o0.w = f2bf((y[3]-mu)*rstd*g[e0+3]+b[e0+3]);
    o1.x = f2bf((y[4]-mu)*rstd*g[e0+4]+b[e0+4]);
    o1.y = f2bf((y[5]-mu)*rstd*g[e0+5]+b[e0+5]);
    o1.z = f2bf((y[6]-mu)*rstd*g[e0+6]+b[e0+6]);
    o1.w = f2bf((y[7]-mu)*rstd*g[e0+7]+b[e0+7]);
    *(ushort4*)&out[(size_t)row * 512 + e0]     = o0;
    *(ushort4*)&out[(size_t)row * 512 + e0 + 4] = o1;
}

// ---------------- weight transpose + cvt: Wt[n][k] = bf16(W[k][n]) ----------------
__global__ __launch_bounds__(256) void cvtT_k(const float* __restrict__ W,
                                              u16* __restrict__ Wt, int K, int N) {
    __shared__ float t[32][33];
    int k0 = blockIdx.x * 32, n0 = blockIdx.y * 32;
    int c = threadIdx.x & 31, r8 = threadIdx.x >> 5;
#pragma unroll
    for (int q = 0; q < 4; q++) {
        int r = r8 * 4 + q;
        t[r][c] = W[(size_t)(k0 + r) * N + n0 + c];
    }
    __syncthreads();
#pragma unroll
    for (int q = 0; q < 4; q++) {
        int r = r8 * 4 + q;
        Wt[(size_t)(n0 + r) * K + k0 + c] = f2bf(t[c][r]);
    }
}

// ---------------- bf16 MFMA GEMM: C[8192 x N] = A[8192 x K] @ Wt[N x K]^T ----------------
template<int EPI>
__global__ __launch_bounds__(256) void gemm_bf16_k(
    const u16* __restrict__ A, const u16* __restrict__ Wt, int N, int K,
    float* __restrict__ Cf, u16* __restrict__ Cb,
    const float* __restrict__ bias, const float* __restrict__ res, int ldres)
{
    __shared__ __align__(16) u16 As[128 * 32];
    __shared__ __align__(16) u16 Bs[128 * 32];
    int tid = threadIdx.x;
    int lane = tid & 63;
    int wm = (tid >> 6) & 1, wn = tid >> 7;
    int r0 = blockIdx.y * 128, n0 = blockIdx.x * 128;
    int arow = tid >> 2, acol = (tid & 3) * 8;
    const u16* ap0 = A  + (size_t)(r0 + arow) * K + acol;
    const u16* ap1 = A  + (size_t)(r0 + 64 + arow) * K + acol;
    const u16* bp0 = Wt + (size_t)(n0 + arow) * K + acol;
    const u16* bp1 = Wt + (size_t)(n0 + 64 + arow) * K + acol;
    u16* al0 = As + tid * 8;
    u16* al1 = As + 2048 + tid * 8;
    u16* bl0 = Bs + tid * 8;
    u16* bl1 = Bs + 2048 + tid * 8;

    f32x4 acc[4][4];
#pragma unroll
    for (int i = 0; i < 4; i++)
#pragma unroll
        for (int j = 0; j < 4; j++) acc[i][j] = (f32x4){0.f, 0.f, 0.f, 0.f};

    int lm = lane & 15, lk = (lane >> 4) * 8;
    for (int k0 = 0; k0 < K; k0 += 32) {
        __builtin_amdgcn_global_load_lds((const GLOBAL_AS unsigned int*)(ap0 + k0), (LDS_AS unsigned int*)al0, 16, 0, 0);
        __builtin_amdgcn_global_load_lds((const GLOBAL_AS unsigned int*)(ap1 + k0), (LDS_AS unsigned int*)al1, 16, 0, 0);
        __builtin_amdgcn_global_load_lds((const GLOBAL_AS unsigned int*)(bp0 + k0), (LDS_AS unsigned int*)bl0, 16, 0, 0);
        __builtin_amdgcn_global_load_lds((const GLOBAL_AS unsigned int*)(bp1 + k0), (LDS_AS unsigned int*)bl1, 16, 0, 0);
        __syncthreads();
        bf16x8 af[4], bfr[4];
#pragma unroll
        for (int f = 0; f < 4; f++) {
            af[f]  = *(const bf16x8*)&As[(wm * 64 + f * 16 + lm) * 32 + lk];
            bfr[f] = *(const bf16x8*)&Bs[(wn * 64 + f * 16 + lm) * 32 + lk];
        }
#pragma unroll
        for (int i = 0; i < 4; i++)
#pragma unroll
            for (int j = 0; j < 4; j++)
                acc[i][j] = __builtin_amdgcn_mfma_f32_16x16x32_bf16(af[i], bfr[j], acc[i][j], 0, 0, 0);
        __syncthreads();
    }
    int lr = (lane >> 4) * 4;
#pragma unroll
    for (int i = 0; i < 4; i++) {
#pragma unroll
        for (int j = 0; j < 4; j++) {
#pragma unroll
            for (int q = 0; q < 4; q++) {
                int row = r0 + wm * 64 + i * 16 + lr + q;
                int col = n0 + wn * 64 + j * 16 + lm;
                float o = acc[i][j][q];
                if (EPI == 0) {
                    Cb[(size_t)row * N + col] = f2bf(o);
                } else if (EPI == 1) {
                    if (col < 1024) Cb[(size_t)row * 1024 + col] = f2bf(o);
                    else            Cf[(size_t)row * 1024 + (col - 1024)] = o;
                } else if (EPI == 2) {
                    o += bias[col] + res[(size_t)row * ldres + col];
                    Cf[(size_t)row * N + col] = o;
                    Cb[(size_t)row * N + col] = f2bf(o);
                } else {
                    o += bias[col];
                    Cf[(size_t)row * N + col] = o;
                }
            }
        }
    }
}

// ---------------- depthwise causal conv (K=4) + bias + SiLU, bf16 in/out ----------------
__global__ __launch_bounds__(256) void conv_k(const u16* __restrict__ xm,
                                              const float* __restrict__ w,
                                              const float* __restrict__ cb,
                                              u16* __restrict__ cact) {
    int idx = blockIdx.x * 256 + threadIdx.x;
    int r = idx >> 8;
    int c = (idx & 255) * 4;
    int t = r & 1023;
    const u16* base = xm + (size_t)(r - t) * I_DIM;
    float4 acc = *(const float4*)&cb[c];
#pragma unroll
    for (int j = 0; j < 4; j++) {
        int tt = t - 3 + j;
        if (tt >= 0) {
            short4 s = *(const short4*)&base[(size_t)tt * I_DIM + c];
            float4 wv = *(const float4*)&w[j * I_DIM + c];
            acc.x = fmaf(bf2f((u16)s.x), wv.x, acc.x);
            acc.y = fmaf(bf2f((u16)s.y), wv.y, acc.y);
            acc.z = fmaf(bf2f((u16)s.z), wv.z, acc.z);
            acc.w = fmaf(bf2f((u16)s.w), wv.w, acc.w);
        }
    }
    acc.x = acc.x / (1.f + __expf(-acc.x));
    acc.y = acc.y / (1.f + __expf(-acc.y));
    acc.z = acc.z / (1.f + __expf(-acc.z));
    acc.w = acc.w / (1.f + __expf(-acc.w));
    ushort4 o;
    o.x = f2bf(acc.x); o.y = f2bf(acc.y); o.z = f2bf(acc.z); o.w = f2bf(acc.w);
    *(ushort4*)&cact[(size_t)r * I_DIM + c] = o;
}

// ---------------- i/f gate pre-activations (bf16 qkv inputs) ----------------
__global__ __launch_bounds__(256) void gates_k(const u16* __restrict__ q,
                                               const u16* __restrict__ k,
                                               const u16* __restrict__ v,
                                               const float* __restrict__ wi,
                                               const float* __restrict__ bi,
                                               const float* __restrict__ wf,
                                               const float* __restrict__ bf,
                                               float* __restrict__ ipre,
                                               float* __restrict__ fpre) {
    int r = blockIdx.x;
    int tid = threadIdx.x;
    float ai[4] = {0,0,0,0}, af[4] = {0,0,0,0};
#pragma unroll
    for (int part = 0; part < 3; part++) {
        const u16* src = (part == 0 ? q : (part == 1 ? k : v)) + (size_t)r * I_DIM;
        const float* wip = wi + part * I_DIM * 4;
        const float* wfp = wf + part * I_DIM * 4;
#pragma unroll
        for (int jj = 0; jj < 4; jj++) {
            int e = tid + jj * 256;
            float xv = bf2f(src[e]);
            float4 w4 = *(const float4*)&wip[e * 4];
            ai[0] = fmaf(xv, w4.x, ai[0]);
            ai[1] = fmaf(xv, w4.y, ai[1]);
            ai[2] = fmaf(xv, w4.z, ai[2]);
            ai[3] = fmaf(xv, w4.w, ai[3]);
            float4 f4v = *(const float4*)&wfp[e * 4];
            af[0] = fmaf(xv, f4v.x, af[0]);
            af[1] = fmaf(xv, f4v.y, af[1]);
            af[2] = fmaf(xv, f4v.z, af[2]);
            af[3] = fmaf(xv, f4v.w, af[3]);
        }
    }
#pragma unroll
    for (int off = 32; off > 0; off >>= 1) {
#pragma unroll
        for (int m = 0; m < 4; m++) {
            ai[m] += __shfl_down(ai[m], off);
            af[m] += __shfl_down(af[m], off);
        }
    }
    __shared__ float red[4][8];
    int wv_ = tid >> 6, lane = tid & 63;
    if (lane == 0) {
#pragma unroll
        for (int m = 0; m < 4; m++) { red[wv_][m] = ai[m]; red[wv_][4 + m] = af[m]; }
    }
    __syncthreads();
    if (tid < 8) {
        float s_ = red[0][tid] + red[1][tid] + red[2][tid] + red[3][tid];
        int b = r >> 10, ss = r & 1023;
        if (tid < 4) ipre[((size_t)(b * 4 + tid)) * 1024 + ss] = s_ + bi[tid];
        else         fpre[((size_t)(b * 4 + (tid - 4))) * 1024 + ss] = s_ + bf[tid - 4];
    }
}

// ---------------- parallel scan per (b,h) ----------------
// outputs: cA = (ipre - lfc) * log2e ; MA = cummax * log2e ; nF = exp(-(lfc+M))
__global__ __launch_bounds__(1024) void scan_k(const float* __restrict__ ipre,
                                               const float* __restrict__ fpre,
                                               float* __restrict__ cA,
                                               float* __restrict__ MA,
                                               float* __restrict__ nF) {
    __shared__ float buf[1024];
    int bh = blockIdx.x, t = threadIdx.x;
    size_t base = (size_t)bh * 1024;
    float fp = fpre[base + t];
    float lf = (fp >= 0.f) ? -log1pf(expf(-fp)) : (fp - log1pf(expf(fp)));
    buf[t] = lf; __syncthreads();
    for (int off = 1; off < 1024; off <<= 1) {
        float u = (t >= off) ? buf[t - off] : 0.f;
        __syncthreads();
        buf[t] += u;
        __syncthreads();
    }
    float lfc = buf[t];
    float c = ipre[base + t] - lfc;
    __syncthreads();
    buf[t] = c; __syncthreads();
    for (int off = 1; off < 1024; off <<= 1) {
        float u = (t >= off) ? buf[t - off] : -3.4e38f;
        __syncthreads();
        buf[t] = fmaxf(buf[t], u);
        __syncthreads();
    }
    float M = buf[t];
    cA[base + t] = c * 1.44269504f;
    MA[base + t] = M * 1.44269504f;
    nF[base + t] = expf(-(lfc + M));
}

// ---------------- MFMA causal mLSTM attention + groupnorm + gating ----------------
// grid (16, H, B), block 256 (4 waves). t-tile 64, s-tile 32, wave w owns d-block w*64.
__global__ __launch_bounds__(256) void attn_k(
    const u16* __restrict__ qg, const u16* __restrict__ kg, const u16* __restrict__ vg,
    const float* __restrict__ c2A, const float* __restrict__ M2A, const float* __restrict__ nFl,
    const u16* __restrict__ cact, const float* __restrict__ zb, u16* __restrict__ hb,
    const float* __restrict__ gng, const float* __restrict__ skip)
{
    __shared__ __align__(16) u16 Vt[256 * 40];   // V^T tile [d][s], pad 40
    __shared__ __align__(16) u16 Ps[64 * 40];    // P bf16 [t][s], pad 40
    __shared__ float rsI[64];
    __shared__ float gS[64 * 4];
    __shared__ float gQ[64 * 4];
    __shared__ float gmu[64], gvr[64];

    int tid = threadIdx.x;
    int w = tid >> 6, l = tid & 63;
    int lm = l & 15, lk = l >> 4;
    int b = blockIdx.z, h = blockIdx.y;
    int T0 = blockIdx.x * 64;
    size_t bh = ((size_t)(b * H_NUM + h)) * S_LEN;

    // Q A-fragments (t-frag i = w) hoisted into registers, all 8 k-steps
    bf16x8 qf[8];
    {
        size_t base = ((size_t)(b * S_LEN + T0 + w * 16 + lm)) * I_DIM + h * DH_ + lk * 8;
#pragma unroll
        for (int ks = 0; ks < 8; ks++) qf[ks] = *(const bf16x8*)&qg[base + ks * 32];
    }
    f32x4 acc[4][4];
#pragma unroll
    for (int i = 0; i < 4; i++)
#pragma unroll
        for (int jd = 0; jd < 4; jd++) acc[i][jd] = (f32x4){0.f, 0.f, 0.f, 0.f};
    float rsum[2][4] = {{0,0,0,0},{0,0,0,0}};
    float m2r[4]; int tg[4];
#pragma unroll
    for (int q = 0; q < 4; q++) {
        tg[q] = T0 + w * 16 + lk * 4 + q;
        m2r[q] = M2A[bh + tg[q]];
    }

    int nst = (T0 >> 5) + 2;
    for (int st = 0; st < nst; st++) {
        int s0 = st * 32;
        // stage V^T
#pragma unroll
        for (int c4 = 0; c4 < 4; c4++) {
            int idx = tid + c4 * 256;
            int s = idx & 31, d0 = (idx >> 5) * 8;
            bf16x8 vv = *(const bf16x8*)&vg[((size_t)(b * S_LEN + s0 + s)) * I_DIM + h * DH_ + d0];
#pragma unroll
            for (int j = 0; j < 8; j++) Vt[(d0 + j) * 40 + s] = (u16)vv[j];
        }
        // scores: wave w computes t-frag w x both s-frags
        f32x4 sacc[2];
        sacc[0] = (f32x4){0.f,0.f,0.f,0.f};
        sacc[1] = (f32x4){0.f,0.f,0.f,0.f};
#pragma unroll
        for (int ks = 0; ks < 8; ks++) {
#pragma unroll
            for (int js = 0; js < 2; js++) {
                bf16x8 kf = *(const bf16x8*)&kg[((size_t)(b * S_LEN + s0 + js * 16 + lm)) * I_DIM + h * DH_ + ks * 32 + lk * 8];
                sacc[js] = __builtin_amdgcn_mfma_f32_16x16x32_bf16(qf[ks], kf, sacc[js], 0, 0, 0);
            }
        }
        // scale by DH^-.5 * exp2(c2[s]-M2[t]), causal mask, round to bf16, rowsum, stage P
#pragma unroll
        for (int js = 0; js < 2; js++) {
            int sg = s0 + js * 16 + lm;
            float c2 = c2A[bh + sg];
#pragma unroll
            for (int q = 0; q < 4; q++) {
                float v = sacc[js][q] * 0.0625f * exp2f(c2 - m2r[q]);
                v = (sg <= tg[q]) ? v : 0.f;
                u16 pb = f2bf(v);
                rsum[js][q] += bf2f(pb);
                Ps[(w * 16 + lk * 4 + q) * 40 + js * 16 + lm] = pb;
            }
        }
        __syncthreads();
        // PV: acc[i][jd] += P[t-frag i] @ Vt[d-frag w*4+jd]
#pragma unroll
        for (int i = 0; i < 4; i++) {
            bf16x8 pa = *(const bf16x8*)&Ps[(i * 16 + lm) * 40 + lk * 8];
#pragma unroll
            for (int jd = 0; jd < 4; jd++) {
                bf16x8 vb = *(const bf16x8*)&Vt[(w * 64 + jd * 16 + lm) * 40 + lk * 8];
                acc[i][jd] = __builtin_amdgcn_mfma_f32_16x16x32_bf16(pa, vb, acc[i][jd], 0, 0, 0);
            }
        }
        __syncthreads();
    }
    // rowsum reduce across the 16 cols (lanes) of each row group
    {
        float rq[4];
#pragma unroll
        for (int q = 0; q < 4; q++) rq[q] = rsum[0][q] + rsum[1][q];
#pragma unroll
        for (int m = 1; m < 16; m <<= 1) {
#pragma unroll
            for (int q = 0; q < 4; q++) rq[q] += __shfl_xor(rq[q], m);
        }
        if (lm == 0) {
#pragma unroll
            for (int q = 0; q < 4; q++) rsI[w * 16 + lk * 4 + q] = rq[q];
        }
    }
    __syncthreads();
    if (tid < 64) {
        float n = fmaxf(fabsf(rsI[tid]), nFl[bh + T0 + tid]);
        rsI[tid] = 1.f / n;
    }
    __syncthreads();
    // normalize + groupnorm partial stats
#pragma unroll
    for (int i = 0; i < 4; i++) {
#pragma unroll
        for (int q = 0; q < 4; q++) {
            int rl = i * 16 + lk * 4 + q;
            float inv = rsI[rl];
            float ps = 0.f, pq = 0.f;
#pragma unroll
            for (int jd = 0; jd < 4; jd++) {
                float v = acc[i][jd][q] * inv;
                acc[i][jd][q] = v;
                ps += v; pq += v * v;
            }
#pragma unroll
            for (int m = 1; m < 16; m <<= 1) {
                ps += __shfl_xor(ps, m);
                pq += __shfl_xor(pq, m);
            }
            if (lm == 0) { gS[rl * 4 + w] = ps; gQ[rl * 4 + w] = pq; }
        }
    }
    __syncthreads();
    if (tid < 64) {
        float s1 = gS[tid*4] + gS[tid*4+1] + gS[tid*4+2] + gS[tid*4+3];
        float s2 = gQ[tid*4] + gQ[tid*4+1] + gQ[tid*4+2] + gQ[tid*4+3];
        float mu = s1 * (1.f / 256.f);
        float var = s2 * (1.f / 256.f) - mu * mu;
        gmu[tid] = mu;
        gvr[tid] = rsqrtf(var + 1e-5f);
    }
    __syncthreads();
    // epilogue: gn_g, +skip*c_act, *silu(z), write bf16
#pragma unroll
    for (int i = 0; i < 4; i++) {
#pragma unroll
        for (int q = 0; q < 4; q++) {
            int rl = i * 16 + lk * 4 + q;
            size_t r = (size_t)b * S_LEN + T0 + rl;
            float mu = gmu[rl], rv = gvr[rl];
#pragma unroll
            for (int jd = 0; jd < 4; jd++) {
                int cix = h * DH_ + w * 64 + jd * 16 + lm;
                float val = (acc[i][jd][q] - mu) * rv * gng[cix];
                float ca = bf2f(cact[r * I_DIM + cix]);
                float z = zb[r * I_DIM + cix];
                float hm = (val + skip[cix] * ca) * (z / (1.f + __expf(-z)));
                hb[r * I_DIM + cix] = f2bf(hm);
            }
        }
    }
}

// ---------------- host launch ----------------
extern "C" void kernel_launch(void* const* d_in, const int* in_sizes, int n_in,
                              void* d_out, int out_size, void* d_ws, size_t ws_size,
                              hipStream_t stream) {
    const float* x      = (const float*)d_in[0];
    const float* ln_g   = (const float*)d_in[1];
    const float* ln_b   = (const float*)d_in[2];
    const float* w_up   = (const float*)d_in[3];
    const float* conv_w = (const float*)d_in[4];
    const float* conv_b = (const float*)d_in[5];
    const float* wq     = (const float*)d_in[6];
    const float* wk     = (const float*)d_in[7];
    const float* wv     = (const float*)d_in[8];
    const float* w_i    = (const float*)d_in[9];
    const float* b_i    = (const float*)d_in[10];
    const float* w_f    = (const float*)d_in[11];
    const float* b_f    = (const float*)d_in[12];
    const float* skip   = (const float*)d_in[13];
    const float* gn_g   = (const float*)d_in[14];
    const float* w_down = (const float*)d_in[15];
    const float* b_down = (const float*)d_in[16];
    const float* w_fin  = (const float*)d_in[17];
    const float* b_fin  = (const float*)d_in[18];

    char* p = (char*)d_ws;
    auto alloc = [&](size_t bytes) { void* r = p; p += (bytes + 255) & ~(size_t)255; return r; };
    float* zbuf  = (float*)alloc((size_t)ROWS * 1024 * 4);
    float* xa    = (float*)alloc((size_t)ROWS * 512 * 4);
    float* xb2   = (float*)alloc((size_t)ROWS * 512 * 4);
    u16*  xln    = (u16*)alloc((size_t)ROWS * 512 * 2);
    u16*  xm     = (u16*)alloc((size_t)ROWS * 1024 * 2);
    u16*  cactb  = (u16*)alloc((size_t)ROWS * 1024 * 2);
    u16*  qbf    = (u16*)alloc((size_t)ROWS * 1024 * 2);
    u16*  kbf    = (u16*)alloc((size_t)ROWS * 1024 * 2);
    u16*  vbf    = (u16*)alloc((size_t)ROWS * 1024 * 2);
    u16*  hbf    = (u16*)alloc((size_t)ROWS * 1024 * 2);
    u16*  xoutb  = (u16*)alloc((size_t)ROWS * 512 * 2);
    u16*  wupT   = (u16*)alloc((size_t)2 * 2048 * 512 * 2);
    u16*  wqT    = (u16*)alloc((size_t)2 * 1024 * 1024 * 2);
    u16*  wkT    = (u16*)alloc((size_t)2 * 1024 * 1024 * 2);
    u16*  wvT    = (u16*)alloc((size_t)2 * 1024 * 1024 * 2);
    u16*  wdT    = (u16*)alloc((size_t)2 * 512 * 1024 * 2);
    u16*  wfT    = (u16*)alloc((size_t)128 * 512 * 2);
    float* ipre  = (float*)alloc(32768 * 4);
    float* fpre  = (float*)alloc(32768 * 4);
    float* cA    = (float*)alloc(32768 * 4);
    float* MA    = (float*)alloc(32768 * 4);
    float* nF    = (float*)alloc(32768 * 4);

    for (int l = 0; l < 2; l++) {
        cvtT_k<<<dim3(16, 64), 256, 0, stream>>>(w_up + (size_t)l * 512 * 2048, wupT + (size_t)l * 2048 * 512, 512, 2048);
        cvtT_k<<<dim3(32, 32), 256, 0, stream>>>(wq + (size_t)l * 1024 * 1024, wqT + (size_t)l * 1024 * 1024, 1024, 1024);
        cvtT_k<<<dim3(32, 32), 256, 0, stream>>>(wk + (size_t)l * 1024 * 1024, wkT + (size_t)l * 1024 * 1024, 1024, 1024);
        cvtT_k<<<dim3(32, 32), 256, 0, stream>>>(wv + (size_t)l * 1024 * 1024, wvT + (size_t)l * 1024 * 1024, 1024, 1024);
        cvtT_k<<<dim3(32, 16), 256, 0, stream>>>(w_down + (size_t)l * 1024 * 512, wdT + (size_t)l * 512 * 1024, 1024, 512);
    }
    cvtT_k<<<dim3(16, 4), 256, 0, stream>>>(w_fin, wfT, 512, 128);

    const float* xin = x;
    for (int l = 0; l < 2; l++) {
        float* xout = (l == 0) ? xa : xb2;
        ln_fused_k<<<ROWS, 64, 0, stream>>>(xin, ln_g + l * 512, ln_b + l * 512, xln);
        gemm_bf16_k<1><<<dim3(16, 64), 256, 0, stream>>>(
            xln, wupT + (size_t)l * 2048 * 512, 2048, 512, zbuf, xm, nullptr, nullptr, 0);
        conv_k<<<ROWS, 256, 0, stream>>>(xm, conv_w + l * 4 * I_DIM, conv_b + l * I_DIM, cactb);
        gemm_bf16_k<0><<<dim3(8, 64), 256, 0, stream>>>(
            xm, wvT + (size_t)l * 1024 * 1024, 1024, 1024, nullptr, vbf, nullptr, nullptr, 0);
        gemm_bf16_k<0><<<dim3(8, 64), 256, 0, stream>>>(
            cactb, wqT + (size_t)l * 1024 * 1024, 1024, 1024, nullptr, qbf, nullptr, nullptr, 0);
        gemm_bf16_k<0><<<dim3(8, 64), 256, 0, stream>>>(
            cactb, wkT + (size_t)l * 1024 * 1024, 1024, 1024, nullptr, kbf, nullptr, nullptr, 0);
        gates_k<<<ROWS, 256, 0, stream>>>(qbf, kbf, vbf,
            w_i + l * 3072 * 4, b_i + l * 4, w_f + l * 3072 * 4, b_f + l * 4, ipre, fpre);
        scan_k<<<32, 1024, 0, stream>>>(ipre, fpre, cA, MA, nF);
        attn_k<<<dim3(16, 4, 8), 256, 0, stream>>>(qbf, kbf, vbf, cA, MA, nF, cactb, zbuf, hbf,
            gn_g + l * I_DIM, skip + l * I_DIM);
        gemm_bf16_k<2><<<dim3(4, 64), 256, 0, stream>>>(
            hbf, wdT + (size_t)l * 512 * 1024, 512, 1024, xout, xoutb,
            b_down + l * 512, xin, 512);
        xin = xout;
    }
    gemm_bf16_k<3><<<dim3(1, 64), 256, 0, stream>>>(
        xoutb, wfT, 128, 512, (float*)d_out, nullptr, b_fin, nullptr, 0);
}

// Round 4
// 755.724 us; speedup vs baseline: 6.6110x; 1.3658x over previous
//
#include <hip/hip_runtime.h>
#include <math.h>

#define S_LEN 1024
#define I_DIM 1024
#define DH_   256
#define H_NUM 4
#define B_NUM 8
#define ROWS  (B_NUM*S_LEN)   // 8192

#define GLOBAL_AS __attribute__((address_space(1)))
#define LDS_AS    __attribute__((address_space(3)))

typedef __attribute__((ext_vector_type(8))) short bf16x8;
typedef __attribute__((ext_vector_type(4))) float f32x4;
typedef unsigned short u16;

__device__ __forceinline__ u16 f2bf(float f) {
    union { float f; unsigned u; } v; v.f = f;
    unsigned r = v.u + 0x7FFF + ((v.u >> 16) & 1);
    return (u16)(r >> 16);
}
__device__ __forceinline__ float bf2f(u16 h) {
    union { unsigned u; float f; } v; v.u = ((unsigned)h) << 16;
    return v.f;
}

// ---------------- fused LayerNorm -> bf16 ----------------
__global__ __launch_bounds__(64) void ln_fused_k(const float* __restrict__ x,
                                                 const float* __restrict__ g,
                                                 const float* __restrict__ b,
                                                 u16* __restrict__ out) {
    int row = blockIdx.x, lane = threadIdx.x;
    const float* xr = x + (size_t)row * 512;
    float4 a = *(const float4*)&xr[lane * 8];
    float4 c = *(const float4*)&xr[lane * 8 + 4];
    float s  = a.x + a.y + a.z + a.w + c.x + c.y + c.z + c.w;
    float s2 = a.x*a.x + a.y*a.y + a.z*a.z + a.w*a.w
             + c.x*c.x + c.y*c.y + c.z*c.z + c.w*c.w;
#pragma unroll
    for (int off = 32; off > 0; off >>= 1) {
        s  += __shfl_down(s, off);
        s2 += __shfl_down(s2, off);
    }
    s = __shfl(s, 0); s2 = __shfl(s2, 0);
    float mu = s * (1.f / 512.f);
    float rstd = rsqrtf(s2 * (1.f / 512.f) - mu * mu + 1e-5f);
    int e0 = lane * 8;
    float y[8] = {a.x,a.y,a.z,a.w,c.x,c.y,c.z,c.w};
    ushort4 o0, o1;
    o0.x = f2bf((y[0]-mu)*rstd*g[e0+0]+b[e0+0]);
    o0.y = f2bf((y[1]-mu)*rstd*g[e0+1]+b[e0+1]);
    o0.z = f2bf((y[2]-mu)*rstd*g[e0+2]+b[e0+2]);
    o0.w = f2bf((y[3]-mu)*rstd*g[e0+3]+b[e0+3]);
    o1.x = f2bf((y[4]-mu)*rstd*g[e0+4]+b[e0+4]);
    o1.y = f2bf((y[5]-mu)*rstd*g[e0+5]+b[e0+5]);
    o1.z = f2bf((y[6]-mu)*rstd*g[e0+6]+b[e0+6]);
    o1.w = f2bf((y[7]-mu)*rstd*g[e0+7]+b[e0+7]);
    *(ushort4*)&out[(size_t)row * 512 + e0]     = o0;
    *(ushort4*)&out[(size_t)row * 512 + e0 + 4] = o1;
}

// ---------------- weight transpose + cvt: Wt[n][k] = bf16(W[k][n]) ----------------
__global__ __launch_bounds__(256) void cvtT_k(const float* __restrict__ W,
                                              u16* __restrict__ Wt, int K, int N) {
    __shared__ float t[32][33];
    int k0 = blockIdx.x * 32, n0 = blockIdx.y * 32;
    int c = threadIdx.x & 31, r8 = threadIdx.x >> 5;
#pragma unroll
    for (int q = 0; q < 4; q++) {
        int r = r8 * 4 + q;
        t[r][c] = W[(size_t)(k0 + r) * N + n0 + c];
    }
    __syncthreads();
#pragma unroll
    for (int q = 0; q < 4; q++) {
        int r = r8 * 4 + q;
        Wt[(size_t)(n0 + r) * K + k0 + c] = f2bf(t[c][r]);
    }
}

// ---------------- V transpose: vt[bh][d][s] = v[b*S+s][h*256+d] ----------------
__global__ __launch_bounds__(256) void vt_k(const u16* __restrict__ v,
                                            u16* __restrict__ vt) {
    __shared__ u16 t[32][34];
    int s0 = blockIdx.x * 32, d0 = blockIdx.y * 32, bh = blockIdx.z;
    int b = bh >> 2, h = bh & 3;
    int c = threadIdx.x & 31, r4 = threadIdx.x >> 5;
#pragma unroll
    for (int q = 0; q < 4; q++) {
        int r = r4 * 4 + q;
        t[r][c] = v[(size_t)(b * 1024 + s0 + r) * I_DIM + h * 256 + d0 + c];
    }
    __syncthreads();
#pragma unroll
    for (int q = 0; q < 4; q++) {
        int r = r4 * 4 + q;
        vt[((size_t)bh * 256 + d0 + r) * 1024 + s0 + c] = t[c][r];
    }
}

// ---------------- bf16 MFMA GEMM: C[8192 x N] = A[8192 x K] @ Wt[N x K]^T ----------------
template<int EPI>
__global__ __launch_bounds__(256) void gemm_bf16_k(
    const u16* __restrict__ A, const u16* __restrict__ Wt, int N, int K,
    float* __restrict__ Cf, u16* __restrict__ Cb,
    const float* __restrict__ bias, const float* __restrict__ res, int ldres)
{
    __shared__ __align__(16) u16 As[128 * 32];
    __shared__ __align__(16) u16 Bs[128 * 32];
    int tid = threadIdx.x;
    int lane = tid & 63;
    int wm = (tid >> 6) & 1, wn = tid >> 7;
    int r0 = blockIdx.y * 128, n0 = blockIdx.x * 128;
    int arow = tid >> 2, acol = (tid & 3) * 8;
    const u16* ap0 = A  + (size_t)(r0 + arow) * K + acol;
    const u16* ap1 = A  + (size_t)(r0 + 64 + arow) * K + acol;
    const u16* bp0 = Wt + (size_t)(n0 + arow) * K + acol;
    const u16* bp1 = Wt + (size_t)(n0 + 64 + arow) * K + acol;
    u16* al0 = As + tid * 8;
    u16* al1 = As + 2048 + tid * 8;
    u16* bl0 = Bs + tid * 8;
    u16* bl1 = Bs + 2048 + tid * 8;

    f32x4 acc[4][4];
#pragma unroll
    for (int i = 0; i < 4; i++)
#pragma unroll
        for (int j = 0; j < 4; j++) acc[i][j] = (f32x4){0.f, 0.f, 0.f, 0.f};

    int lm = lane & 15, lk = (lane >> 4) * 8;
    for (int k0 = 0; k0 < K; k0 += 32) {
        __builtin_amdgcn_global_load_lds((const GLOBAL_AS unsigned int*)(ap0 + k0), (LDS_AS unsigned int*)al0, 16, 0, 0);
        __builtin_amdgcn_global_load_lds((const GLOBAL_AS unsigned int*)(ap1 + k0), (LDS_AS unsigned int*)al1, 16, 0, 0);
        __builtin_amdgcn_global_load_lds((const GLOBAL_AS unsigned int*)(bp0 + k0), (LDS_AS unsigned int*)bl0, 16, 0, 0);
        __builtin_amdgcn_global_load_lds((const GLOBAL_AS unsigned int*)(bp1 + k0), (LDS_AS unsigned int*)bl1, 16, 0, 0);
        __syncthreads();
        bf16x8 af[4], bfr[4];
#pragma unroll
        for (int f = 0; f < 4; f++) {
            af[f]  = *(const bf16x8*)&As[(wm * 64 + f * 16 + lm) * 32 + lk];
            bfr[f] = *(const bf16x8*)&Bs[(wn * 64 + f * 16 + lm) * 32 + lk];
        }
#pragma unroll
        for (int i = 0; i < 4; i++)
#pragma unroll
            for (int j = 0; j < 4; j++)
                acc[i][j] = __builtin_amdgcn_mfma_f32_16x16x32_bf16(af[i], bfr[j], acc[i][j], 0, 0, 0);
        __syncthreads();
    }
    int lr = (lane >> 4) * 4;
#pragma unroll
    for (int i = 0; i < 4; i++) {
#pragma unroll
        for (int j = 0; j < 4; j++) {
#pragma unroll
            for (int q = 0; q < 4; q++) {
                int row = r0 + wm * 64 + i * 16 + lr + q;
                int col = n0 + wn * 64 + j * 16 + lm;
                float o = acc[i][j][q];
                if (EPI == 0) {
                    Cb[(size_t)row * N + col] = f2bf(o);
                } else if (EPI == 1) {
                    if (col < 1024) Cb[(size_t)row * 1024 + col] = f2bf(o);
                    else            Cf[(size_t)row * 1024 + (col - 1024)] = o;
                } else if (EPI == 2) {
                    o += bias[col] + res[(size_t)row * ldres + col];
                    Cf[(size_t)row * N + col] = o;
                    Cb[(size_t)row * N + col] = f2bf(o);
                } else {
                    o += bias[col];
                    Cf[(size_t)row * N + col] = o;
                }
            }
        }
    }
}

// ---------------- depthwise causal conv (K=4) + bias + SiLU, bf16 in/out ----------------
__global__ __launch_bounds__(256) void conv_k(const u16* __restrict__ xm,
                                              const float* __restrict__ w,
                                              const float* __restrict__ cb,
                                              u16* __restrict__ cact) {
    int idx = blockIdx.x * 256 + threadIdx.x;
    int r = idx >> 8;
    int c = (idx & 255) * 4;
    int t = r & 1023;
    const u16* base = xm + (size_t)(r - t) * I_DIM;
    float4 acc = *(const float4*)&cb[c];
#pragma unroll
    for (int j = 0; j < 4; j++) {
        int tt = t - 3 + j;
        if (tt >= 0) {
            short4 s = *(const short4*)&base[(size_t)tt * I_DIM + c];
            float4 wv = *(const float4*)&w[j * I_DIM + c];
            acc.x = fmaf(bf2f((u16)s.x), wv.x, acc.x);
            acc.y = fmaf(bf2f((u16)s.y), wv.y, acc.y);
            acc.z = fmaf(bf2f((u16)s.z), wv.z, acc.z);
            acc.w = fmaf(bf2f((u16)s.w), wv.w, acc.w);
        }
    }
    acc.x = acc.x / (1.f + __expf(-acc.x));
    acc.y = acc.y / (1.f + __expf(-acc.y));
    acc.z = acc.z / (1.f + __expf(-acc.z));
    acc.w = acc.w / (1.f + __expf(-acc.w));
    ushort4 o;
    o.x = f2bf(acc.x); o.y = f2bf(acc.y); o.z = f2bf(acc.z); o.w = f2bf(acc.w);
    *(ushort4*)&cact[(size_t)r * I_DIM + c] = o;
}

// ---------------- i/f gate pre-activations (bf16 qkv inputs) ----------------
__global__ __launch_bounds__(256) void gates_k(const u16* __restrict__ q,
                                               const u16* __restrict__ k,
                                               const u16* __restrict__ v,
                                               const float* __restrict__ wi,
                                               const float* __restrict__ bi,
                                               const float* __restrict__ wf,
                                               const float* __restrict__ bf,
                                               float* __restrict__ ipre,
                                               float* __restrict__ fpre) {
    int r = blockIdx.x;
    int tid = threadIdx.x;
    float ai[4] = {0,0,0,0}, af[4] = {0,0,0,0};
#pragma unroll
    for (int part = 0; part < 3; part++) {
        const u16* src = (part == 0 ? q : (part == 1 ? k : v)) + (size_t)r * I_DIM;
        const float* wip = wi + part * I_DIM * 4;
        const float* wfp = wf + part * I_DIM * 4;
#pragma unroll
        for (int jj = 0; jj < 4; jj++) {
            int e = tid + jj * 256;
            float xv = bf2f(src[e]);
            float4 w4 = *(const float4*)&wip[e * 4];
            ai[0] = fmaf(xv, w4.x, ai[0]);
            ai[1] = fmaf(xv, w4.y, ai[1]);
            ai[2] = fmaf(xv, w4.z, ai[2]);
            ai[3] = fmaf(xv, w4.w, ai[3]);
            float4 f4v = *(const float4*)&wfp[e * 4];
            af[0] = fmaf(xv, f4v.x, af[0]);
            af[1] = fmaf(xv, f4v.y, af[1]);
            af[2] = fmaf(xv, f4v.z, af[2]);
            af[3] = fmaf(xv, f4v.w, af[3]);
        }
    }
#pragma unroll
    for (int off = 32; off > 0; off >>= 1) {
#pragma unroll
        for (int m = 0; m < 4; m++) {
            ai[m] += __shfl_down(ai[m], off);
            af[m] += __shfl_down(af[m], off);
        }
    }
    __shared__ float red[4][8];
    int wv_ = tid >> 6, lane = tid & 63;
    if (lane == 0) {
#pragma unroll
        for (int m = 0; m < 4; m++) { red[wv_][m] = ai[m]; red[wv_][4 + m] = af[m]; }
    }
    __syncthreads();
    if (tid < 8) {
        float s_ = red[0][tid] + red[1][tid] + red[2][tid] + red[3][tid];
        int b = r >> 10, ss = r & 1023;
        if (tid < 4) ipre[((size_t)(b * 4 + tid)) * 1024 + ss] = s_ + bi[tid];
        else         fpre[((size_t)(b * 4 + (tid - 4))) * 1024 + ss] = s_ + bf[tid - 4];
    }
}

// ---------------- parallel scan per (b,h) ----------------
__global__ __launch_bounds__(1024) void scan_k(const float* __restrict__ ipre,
                                               const float* __restrict__ fpre,
                                               float* __restrict__ cA,
                                               float* __restrict__ MA,
                                               float* __restrict__ nF) {
    __shared__ float buf[1024];
    int bh = blockIdx.x, t = threadIdx.x;
    size_t base = (size_t)bh * 1024;
    float fp = fpre[base + t];
    float lf = (fp >= 0.f) ? -log1pf(expf(-fp)) : (fp - log1pf(expf(fp)));
    buf[t] = lf; __syncthreads();
    for (int off = 1; off < 1024; off <<= 1) {
        float u = (t >= off) ? buf[t - off] : 0.f;
        __syncthreads();
        buf[t] += u;
        __syncthreads();
    }
    float lfc = buf[t];
    float c = ipre[base + t] - lfc;
    __syncthreads();
    buf[t] = c; __syncthreads();
    for (int off = 1; off < 1024; off <<= 1) {
        float u = (t >= off) ? buf[t - off] : -3.4e38f;
        __syncthreads();
        buf[t] = fmaxf(buf[t], u);
        __syncthreads();
    }
    float M = buf[t];
    cA[base + t] = c * 1.44269504f;
    MA[base + t] = M * 1.44269504f;
    nF[base + t] = expf(-(lfc + M));
}

// ---------------- MFMA causal mLSTM attention + groupnorm + gating ----------------
// grid (16, H, B), block 256 (4 waves). t-tile 64, s-tile 32.
// K,V staged via global_load_lds double-buffered with pre-swizzled source.
__global__ __launch_bounds__(256) void attn_k(
    const u16* __restrict__ qg, const u16* __restrict__ kg, const u16* __restrict__ vt,
    const float* __restrict__ c2A, const float* __restrict__ M2A, const float* __restrict__ nFl,
    const u16* __restrict__ cact, const float* __restrict__ zb, u16* __restrict__ hb,
    const float* __restrict__ gng, const float* __restrict__ skip)
{
    __shared__ __align__(16) u16 Kb[2][32 * 256];   // [s-row][512B], chunk-swizzled
    __shared__ __align__(16) u16 Vb[2][256 * 32];   // [d-row][64B], pair-swizzled
    __shared__ __align__(16) u16 Ps[64 * 40];
    __shared__ float rsI[64];
    __shared__ float gS[64 * 4];
    __shared__ float gQ[64 * 4];
    __shared__ float gmu[64], gvr[64];

    int tid = threadIdx.x;
    int w = tid >> 6, l = tid & 63;
    int lm = l & 15, lk = l >> 4;
    int b = blockIdx.z, h = blockIdx.y;
    int T0 = blockIdx.x * 64;
    int bh32 = b * H_NUM + h;
    size_t bh = (size_t)bh32 * S_LEN;

    // Q A-fragments hoisted
    bf16x8 qf[8];
    {
        size_t base = ((size_t)(b * S_LEN + T0 + w * 16 + lm)) * I_DIM + h * DH_ + lk * 8;
#pragma unroll
        for (int ks = 0; ks < 8; ks++) qf[ks] = *(const bf16x8*)&qg[base + ks * 32];
    }
    f32x4 acc[4][4];
#pragma unroll
    for (int i = 0; i < 4; i++)
#pragma unroll
        for (int jd = 0; jd < 4; jd++) acc[i][jd] = (f32x4){0.f, 0.f, 0.f, 0.f};
    float rsum[2][4] = {{0,0,0,0},{0,0,0,0}};
    float m2r[4]; int tg[4];
#pragma unroll
    for (int q = 0; q < 4; q++) {
        tg[q] = T0 + w * 16 + lk * 4 + q;
        m2r[q] = M2A[bh + tg[q]];
    }

    const size_t krow0 = ((size_t)(b * S_LEN)) * I_DIM + h * DH_;   // + (s0+row)*I_DIM + chunk*8
    const size_t vrow0 = (size_t)bh32 * 256 * S_LEN;                // + d*S_LEN + s0 + chunk*8

    // staging: one tile (32 s) of K and V into buffer half bs
    auto stage = [&](int s0, int bs) {
#pragma unroll
        for (int r = 0; r < 4; r++) {
            int q = r * 256 + tid;          // K slot (16B units)
            int row = q >> 5, cl = q & 31;
            int cs = cl ^ (row & 7);
            const u16* src = kg + krow0 + (size_t)(s0 + row) * I_DIM + cs * 8;
            __builtin_amdgcn_global_load_lds((const GLOBAL_AS unsigned int*)src,
                                             (LDS_AS unsigned int*)&Kb[bs][q * 8], 16, 0, 0);
        }
#pragma unroll
        for (int r = 0; r < 4; r++) {
            int q = r * 256 + tid;          // V slot (16B units)
            int dpair = q >> 3, cp = q & 7;
            int u = cp ^ (dpair & 7);
            int d = dpair * 2 + (u >> 2), c = u & 3;
            const u16* src = vt + vrow0 + (size_t)d * S_LEN + s0 + c * 8;
            __builtin_amdgcn_global_load_lds((const GLOBAL_AS unsigned int*)src,
                                             (LDS_AS unsigned int*)&Vb[bs][q * 8], 16, 0, 0);
        }
    };

    int nst = (T0 >> 5) + 2;
    stage(0, 0);
    for (int st = 0; st < nst; st++) {
        int s0 = st * 32;
        int cur = st & 1;
        __syncthreads();   // stage(st) landed; Ps consumed by previous PV
        // ---- QK^T from Kb[cur] ----
        f32x4 sacc[2];
        sacc[0] = (f32x4){0.f,0.f,0.f,0.f};
        sacc[1] = (f32x4){0.f,0.f,0.f,0.f};
#pragma unroll
        for (int ks = 0; ks < 8; ks++) {
#pragma unroll
            for (int js = 0; js < 2; js++) {
                int row = js * 16 + lm;
                int ch = (ks * 4 + lk) ^ (row & 7);
                bf16x8 kf = *(const bf16x8*)&Kb[cur][row * 256 + ch * 8];
                sacc[js] = __builtin_amdgcn_mfma_f32_16x16x32_bf16(qf[ks], kf, sacc[js], 0, 0, 0);
            }
        }
        // ---- scale, mask, round, rowsum, stage P ----
#pragma unroll
        for (int js = 0; js < 2; js++) {
            int sg = s0 + js * 16 + lm;
            float c2 = c2A[bh + sg];
#pragma unroll
            for (int q = 0; q < 4; q++) {
                float v = sacc[js][q] * 0.0625f * exp2f(c2 - m2r[q]);
                v = (sg <= tg[q]) ? v : 0.f;
                u16 pb = f2bf(v);
                rsum[js][q] += bf2f(pb);
                Ps[(w * 16 + lk * 4 + q) * 40 + js * 16 + lm] = pb;
            }
        }
        __syncthreads();   // Ps visible to all waves
        if (st + 1 < nst) stage(s0 + 32, cur ^ 1);
        // ---- PV from Ps + Vb[cur] ----
        bf16x8 vf[4];
#pragma unroll
        for (int jd = 0; jd < 4; jd++) {
            int d = w * 64 + jd * 16 + lm;
            int cp = (((d & 1) << 2) + lk) ^ ((d >> 1) & 7);
            vf[jd] = *(const bf16x8*)&Vb[cur][((d >> 1) * 8 + cp) * 8];
        }
#pragma unroll
        for (int i = 0; i < 4; i++) {
            bf16x8 pa = *(const bf16x8*)&Ps[(i * 16 + lm) * 40 + lk * 8];
#pragma unroll
            for (int jd = 0; jd < 4; jd++)
                acc[i][jd] = __builtin_amdgcn_mfma_f32_16x16x32_bf16(pa, vf[jd], acc[i][jd], 0, 0, 0);
        }
    }
    // ---- rowsum reduce ----
    {
        float rq[4];
#pragma unroll
        for (int q = 0; q < 4; q++) rq[q] = rsum[0][q] + rsum[1][q];
#pragma unroll
        for (int m = 1; m < 16; m <<= 1) {
#pragma unroll
            for (int q = 0; q < 4; q++) rq[q] += __shfl_xor(rq[q], m);
        }
        if (lm == 0) {
#pragma unroll
            for (int q = 0; q < 4; q++) rsI[w * 16 + lk * 4 + q] = rq[q];
        }
    }
    __syncthreads();
    if (tid < 64) {
        float n = fmaxf(fabsf(rsI[tid]), nFl[bh + T0 + tid]);
        rsI[tid] = 1.f / n;
    }
    __syncthreads();
    // ---- normalize + groupnorm stats ----
#pragma unroll
    for (int i = 0; i < 4; i++) {
#pragma unroll
        for (int q = 0; q < 4; q++) {
            int rl = i * 16 + lk * 4 + q;
            float inv = rsI[rl];
            float ps = 0.f, pq = 0.f;
#pragma unroll
            for (int jd = 0; jd < 4; jd++) {
                float v = acc[i][jd][q] * inv;
                acc[i][jd][q] = v;
                ps += v; pq += v * v;
            }
#pragma unroll
            for (int m = 1; m < 16; m <<= 1) {
                ps += __shfl_xor(ps, m);
                pq += __shfl_xor(pq, m);
            }
            if (lm == 0) { gS[rl * 4 + w] = ps; gQ[rl * 4 + w] = pq; }
        }
    }
    __syncthreads();
    if (tid < 64) {
        float s1 = gS[tid*4] + gS[tid*4+1] + gS[tid*4+2] + gS[tid*4+3];
        float s2 = gQ[tid*4] + gQ[tid*4+1] + gQ[tid*4+2] + gQ[tid*4+3];
        float mu = s1 * (1.f / 256.f);
        float var = s2 * (1.f / 256.f) - mu * mu;
        gmu[tid] = mu;
        gvr[tid] = rsqrtf(var + 1e-5f);
    }
    __syncthreads();
    // ---- epilogue ----
#pragma unroll
    for (int i = 0; i < 4; i++) {
#pragma unroll
        for (int q = 0; q < 4; q++) {
            int rl = i * 16 + lk * 4 + q;
            size_t r = (size_t)b * S_LEN + T0 + rl;
            float mu = gmu[rl], rv = gvr[rl];
#pragma unroll
            for (int jd = 0; jd < 4; jd++) {
                int cix = h * DH_ + w * 64 + jd * 16 + lm;
                float val = (acc[i][jd][q] - mu) * rv * gng[cix];
                float ca = bf2f(cact[r * I_DIM + cix]);
                float z = zb[r * I_DIM + cix];
                float hm = (val + skip[cix] * ca) * (z / (1.f + __expf(-z)));
                hb[r * I_DIM + cix] = f2bf(hm);
            }
        }
    }
}

// ---------------- host launch ----------------
extern "C" void kernel_launch(void* const* d_in, const int* in_sizes, int n_in,
                              void* d_out, int out_size, void* d_ws, size_t ws_size,
                              hipStream_t stream) {
    const float* x      = (const float*)d_in[0];
    const float* ln_g   = (const float*)d_in[1];
    const float* ln_b   = (const float*)d_in[2];
    const float* w_up   = (const float*)d_in[3];
    const float* conv_w = (const float*)d_in[4];
    const float* conv_b = (const float*)d_in[5];
    const float* wq     = (const float*)d_in[6];
    const float* wk     = (const float*)d_in[7];
    const float* wv     = (const float*)d_in[8];
    const float* w_i    = (const float*)d_in[9];
    const float* b_i    = (const float*)d_in[10];
    const float* w_f    = (const float*)d_in[11];
    const float* b_f    = (const float*)d_in[12];
    const float* skip   = (const float*)d_in[13];
    const float* gn_g   = (const float*)d_in[14];
    const float* w_down = (const float*)d_in[15];
    const float* b_down = (const float*)d_in[16];
    const float* w_fin  = (const float*)d_in[17];
    const float* b_fin  = (const float*)d_in[18];

    char* p = (char*)d_ws;
    auto alloc = [&](size_t bytes) { void* r = p; p += (bytes + 255) & ~(size_t)255; return r; };
    float* zbuf  = (float*)alloc((size_t)ROWS * 1024 * 4);
    float* xa    = (float*)alloc((size_t)ROWS * 512 * 4);
    float* xb2   = (float*)alloc((size_t)ROWS * 512 * 4);
    u16*  xln    = (u16*)alloc((size_t)ROWS * 512 * 2);
    u16*  xm     = (u16*)alloc((size_t)ROWS * 1024 * 2);
    u16*  cactb  = (u16*)alloc((size_t)ROWS * 1024 * 2);
    u16*  qbf    = (u16*)alloc((size_t)ROWS * 1024 * 2);
    u16*  kbf    = (u16*)alloc((size_t)ROWS * 1024 * 2);
    u16*  vbf    = (u16*)alloc((size_t)ROWS * 1024 * 2);
    u16*  vtg    = (u16*)alloc((size_t)32 * 256 * 1024 * 2);
    u16*  hbf    = (u16*)alloc((size_t)ROWS * 1024 * 2);
    u16*  xoutb  = (u16*)alloc((size_t)ROWS * 512 * 2);
    u16*  wupT   = (u16*)alloc((size_t)2 * 2048 * 512 * 2);
    u16*  wqT    = (u16*)alloc((size_t)2 * 1024 * 1024 * 2);
    u16*  wkT    = (u16*)alloc((size_t)2 * 1024 * 1024 * 2);
    u16*  wvT    = (u16*)alloc((size_t)2 * 1024 * 1024 * 2);
    u16*  wdT    = (u16*)alloc((size_t)2 * 512 * 1024 * 2);
    u16*  wfT    = (u16*)alloc((size_t)128 * 512 * 2);
    float* ipre  = (float*)alloc(32768 * 4);
    float* fpre  = (float*)alloc(32768 * 4);
    float* cA    = (float*)alloc(32768 * 4);
    float* MA    = (float*)alloc(32768 * 4);
    float* nF    = (float*)alloc(32768 * 4);

    for (int l = 0; l < 2; l++) {
        cvtT_k<<<dim3(16, 64), 256, 0, stream>>>(w_up + (size_t)l * 512 * 2048, wupT + (size_t)l * 2048 * 512, 512, 2048);
        cvtT_k<<<dim3(32, 32), 256, 0, stream>>>(wq + (size_t)l * 1024 * 1024, wqT + (size_t)l * 1024 * 1024, 1024, 1024);
        cvtT_k<<<dim3(32, 32), 256, 0, stream>>>(wk + (size_t)l * 1024 * 1024, wkT + (size_t)l * 1024 * 1024, 1024, 1024);
        cvtT_k<<<dim3(32, 32), 256, 0, stream>>>(wv + (size_t)l * 1024 * 1024, wvT + (size_t)l * 1024 * 1024, 1024, 1024);
        cvtT_k<<<dim3(32, 16), 256, 0, stream>>>(w_down + (size_t)l * 1024 * 512, wdT + (size_t)l * 512 * 1024, 1024, 512);
    }
    cvtT_k<<<dim3(16, 4), 256, 0, stream>>>(w_fin, wfT, 512, 128);

    const float* xin = x;
    for (int l = 0; l < 2; l++) {
        float* xout = (l == 0) ? xa : xb2;
        ln_fused_k<<<ROWS, 64, 0, stream>>>(xin, ln_g + l * 512, ln_b + l * 512, xln);
        gemm_bf16_k<1><<<dim3(16, 64), 256, 0, stream>>>(
            xln, wupT + (size_t)l * 2048 * 512, 2048, 512, zbuf, xm, nullptr, nullptr, 0);
        conv_k<<<ROWS, 256, 0, stream>>>(xm, conv_w + l * 4 * I_DIM, conv_b + l * I_DIM, cactb);
        gemm_bf16_k<0><<<dim3(8, 64), 256, 0, stream>>>(
            xm, wvT + (size_t)l * 1024 * 1024, 1024, 1024, nullptr, vbf, nullptr, nullptr, 0);
        gemm_bf16_k<0><<<dim3(8, 64), 256, 0, stream>>>(
            cactb, wqT + (size_t)l * 1024 * 1024, 1024, 1024, nullptr, qbf, nullptr, nullptr, 0);
        gemm_bf16_k<0><<<dim3(8, 64), 256, 0, stream>>>(
            cactb, wkT + (size_t)l * 1024 * 1024, 1024, 1024, nullptr, kbf, nullptr, nullptr, 0);
        vt_k<<<dim3(32, 8, 32), 256, 0, stream>>>(vbf, vtg);
        gates_k<<<ROWS, 256, 0, stream>>>(qbf, kbf, vbf,
            w_i + l * 3072 * 4, b_i + l * 4, w_f + l * 3072 * 4, b_f + l * 4, ipre, fpre);
        scan_k<<<32, 1024, 0, stream>>>(ipre, fpre, cA, MA, nF);
        attn_k<<<dim3(16, 4, 8), 256, 0, stream>>>(qbf, kbf, vtg, cA, MA, nF, cactb, zbuf, hbf,
            gn_g + l * I_DIM, skip + l * I_DIM);
        gemm_bf16_k<2><<<dim3(4, 64), 256, 0, stream>>>(
            hbf, wdT + (size_t)l * 512 * 1024, 512, 1024, xout, xoutb,
            b_down + l * 512, xin, 512);
        xin = xout;
    }
    gemm_bf16_k<3><<<dim3(1, 64), 256, 0, stream>>>(
        xoutb, wfT, 128, 512, (float*)d_out, nullptr, b_fin, nullptr, 0);
}

// Round 5
// 696.458 us; speedup vs baseline: 7.1736x; 1.0851x over previous
//
#include <hip/hip_runtime.h>
#include <math.h>

#define S_LEN 1024
#define I_DIM 1024
#define DH_   256
#define H_NUM 4
#define B_NUM 8
#define ROWS  (B_NUM*S_LEN)   // 8192

#define GLOBAL_AS __attribute__((address_space(1)))
#define LDS_AS    __attribute__((address_space(3)))

#define VM0    asm volatile("s_waitcnt vmcnt(0)" ::: "memory")
#define LGKM0  asm volatile("s_waitcnt lgkmcnt(0)" ::: "memory")
#define BAR    __builtin_amdgcn_s_barrier()
#define SFENCE __builtin_amdgcn_sched_barrier(0)

typedef __attribute__((ext_vector_type(8))) short bf16x8;
typedef __attribute__((ext_vector_type(4))) float f32x4;
typedef unsigned short u16;

__device__ __forceinline__ u16 f2bf(float f) {
    union { float f; unsigned u; } v; v.f = f;
    unsigned r = v.u + 0x7FFF + ((v.u >> 16) & 1);
    return (u16)(r >> 16);
}
__device__ __forceinline__ float bf2f(u16 h) {
    union { unsigned u; float f; } v; v.u = ((unsigned)h) << 16;
    return v.f;
}

// ---------------- fused LayerNorm -> bf16 ----------------
__global__ __launch_bounds__(64) void ln_fused_k(const float* __restrict__ x,
                                                 const float* __restrict__ g,
                                                 const float* __restrict__ b,
                                                 u16* __restrict__ out) {
    int row = blockIdx.x, lane = threadIdx.x;
    const float* xr = x + (size_t)row * 512;
    float4 a = *(const float4*)&xr[lane * 8];
    float4 c = *(const float4*)&xr[lane * 8 + 4];
    float s  = a.x + a.y + a.z + a.w + c.x + c.y + c.z + c.w;
    float s2 = a.x*a.x + a.y*a.y + a.z*a.z + a.w*a.w
             + c.x*c.x + c.y*c.y + c.z*c.z + c.w*c.w;
#pragma unroll
    for (int off = 32; off > 0; off >>= 1) {
        s  += __shfl_down(s, off);
        s2 += __shfl_down(s2, off);
    }
    s = __shfl(s, 0); s2 = __shfl(s2, 0);
    float mu = s * (1.f / 512.f);
    float rstd = rsqrtf(s2 * (1.f / 512.f) - mu * mu + 1e-5f);
    int e0 = lane * 8;
    float y[8] = {a.x,a.y,a.z,a.w,c.x,c.y,c.z,c.w};
    ushort4 o0, o1;
    o0.x = f2bf((y[0]-mu)*rstd*g[e0+0]+b[e0+0]);
    o0.y = f2bf((y[1]-mu)*rstd*g[e0+1]+b[e0+1]);
    o0.z = f2bf((y[2]-mu)*rstd*g[e0+2]+b[e0+2]);
    o0.w = f2bf((y[3]-mu)*rstd*g[e0+3]+b[e0+3]);
    o1.x = f2bf((y[4]-mu)*rstd*g[e0+4]+b[e0+4]);
    o1.y = f2bf((y[5]-mu)*rstd*g[e0+5]+b[e0+5]);
    o1.z = f2bf((y[6]-mu)*rstd*g[e0+6]+b[e0+6]);
    o1.w = f2bf((y[7]-mu)*rstd*g[e0+7]+b[e0+7]);
    *(ushort4*)&out[(size_t)row * 512 + e0]     = o0;
    *(ushort4*)&out[(size_t)row * 512 + e0 + 4] = o1;
}

// ---------------- weight transpose + cvt: Wt[n][k] = bf16(W[k][n]) ----------------
__global__ __launch_bounds__(256) void cvtT_k(const float* __restrict__ W,
                                              u16* __restrict__ Wt, int K, int N) {
    __shared__ float t[32][33];
    int k0 = blockIdx.x * 32, n0 = blockIdx.y * 32;
    int c = threadIdx.x & 31, r8 = threadIdx.x >> 5;
#pragma unroll
    for (int q = 0; q < 4; q++) {
        int r = r8 * 4 + q;
        t[r][c] = W[(size_t)(k0 + r) * N + n0 + c];
    }
    __syncthreads();
#pragma unroll
    for (int q = 0; q < 4; q++) {
        int r = r8 * 4 + q;
        Wt[(size_t)(n0 + r) * K + k0 + c] = f2bf(t[c][r]);
    }
}

// ---------------- V transpose: vt[bh][d][s] = v[b*S+s][h*256+d] ----------------
__global__ __launch_bounds__(256) void vt_k(const u16* __restrict__ v,
                                            u16* __restrict__ vt) {
    __shared__ u16 t[32][34];
    int s0 = blockIdx.x * 32, d0 = blockIdx.y * 32, bh = blockIdx.z;
    int b = bh >> 2, h = bh & 3;
    int c = threadIdx.x & 31, r4 = threadIdx.x >> 5;
#pragma unroll
    for (int q = 0; q < 4; q++) {
        int r = r4 * 4 + q;
        t[r][c] = v[(size_t)(b * 1024 + s0 + r) * I_DIM + h * 256 + d0 + c];
    }
    __syncthreads();
#pragma unroll
    for (int q = 0; q < 4; q++) {
        int r = r4 * 4 + q;
        vt[((size_t)bh * 256 + d0 + r) * 1024 + s0 + c] = t[c][r];
    }
}

// ---------------- bf16 MFMA GEMM, 2-phase dbuf + XCD swizzle ----------------
// C[8192 x N] = A[8192 x K] @ Wt[N x K]^T
template<int EPI>
__global__ __launch_bounds__(256) void gemm_bf16_k(
    const u16* __restrict__ A, const u16* __restrict__ Wt, int N, int K,
    float* __restrict__ Cf, u16* __restrict__ Cb,
    const float* __restrict__ bias, const float* __restrict__ res, int ldres)
{
    __shared__ __align__(16) u16 As[2][128 * 32];
    __shared__ __align__(16) u16 Bs[2][128 * 32];
    int tid = threadIdx.x;
    int lane = tid & 63;
    int wm = (tid >> 6) & 1, wn = tid >> 7;
    // XCD-aware bijective swizzle (nwg % 8 == 0 for all call sites)
    int gx = gridDim.x;
    int nwg = gx * gridDim.y;
    int bid = blockIdx.y * gx + blockIdx.x;
    int cpx = nwg >> 3;
    int swz = (bid & 7) * cpx + (bid >> 3);
    int r0 = (swz / gx) * 128, n0 = (swz % gx) * 128;

    int arow = tid >> 2, acol = (tid & 3) * 8;
    const u16* ap0 = A  + (size_t)(r0 + arow) * K + acol;
    const u16* ap1 = A  + (size_t)(r0 + 64 + arow) * K + acol;
    const u16* bp0 = Wt + (size_t)(n0 + arow) * K + acol;
    const u16* bp1 = Wt + (size_t)(n0 + 64 + arow) * K + acol;

    auto stage = [&](int kt, int bs) {
        int koff = kt * 32;
        __builtin_amdgcn_global_load_lds((const GLOBAL_AS unsigned int*)(ap0 + koff), (LDS_AS unsigned int*)&As[bs][tid * 8], 16, 0, 0);
        __builtin_amdgcn_global_load_lds((const GLOBAL_AS unsigned int*)(ap1 + koff), (LDS_AS unsigned int*)&As[bs][2048 + tid * 8], 16, 0, 0);
        __builtin_amdgcn_global_load_lds((const GLOBAL_AS unsigned int*)(bp0 + koff), (LDS_AS unsigned int*)&Bs[bs][tid * 8], 16, 0, 0);
        __builtin_amdgcn_global_load_lds((const GLOBAL_AS unsigned int*)(bp1 + koff), (LDS_AS unsigned int*)&Bs[bs][2048 + tid * 8], 16, 0, 0);
    };

    f32x4 acc[4][4];
#pragma unroll
    for (int i = 0; i < 4; i++)
#pragma unroll
        for (int j = 0; j < 4; j++) acc[i][j] = (f32x4){0.f, 0.f, 0.f, 0.f};

    int lm = lane & 15, lk = (lane >> 4) * 8;
    int nt = K >> 5;
    stage(0, 0);
    VM0; BAR; SFENCE;
    for (int t = 0; t < nt; ++t) {
        int cur = t & 1;
        if (t + 1 < nt) stage(t + 1, cur ^ 1);
        bf16x8 af[4], bfr[4];
#pragma unroll
        for (int f = 0; f < 4; f++) {
            af[f]  = *(const bf16x8*)&As[cur][(wm * 64 + f * 16 + lm) * 32 + lk];
            bfr[f] = *(const bf16x8*)&Bs[cur][(wn * 64 + f * 16 + lm) * 32 + lk];
        }
#pragma unroll
        for (int i = 0; i < 4; i++)
#pragma unroll
            for (int j = 0; j < 4; j++)
                acc[i][j] = __builtin_amdgcn_mfma_f32_16x16x32_bf16(af[i], bfr[j], acc[i][j], 0, 0, 0);
        VM0; BAR; SFENCE;
    }
    int lr = (lane >> 4) * 4;
#pragma unroll
    for (int i = 0; i < 4; i++) {
#pragma unroll
        for (int j = 0; j < 4; j++) {
#pragma unroll
            for (int q = 0; q < 4; q++) {
                int row = r0 + wm * 64 + i * 16 + lr + q;
                int col = n0 + wn * 64 + j * 16 + lm;
                float o = acc[i][j][q];
                if (EPI == 0) {
                    Cb[(size_t)row * N + col] = f2bf(o);
                } else if (EPI == 1) {
                    if (col < 1024) Cb[(size_t)row * 1024 + col] = f2bf(o);
                    else            Cf[(size_t)row * 1024 + (col - 1024)] = o;
                } else if (EPI == 2) {
                    o += bias[col] + res[(size_t)row * ldres + col];
                    Cf[(size_t)row * N + col] = o;
                    Cb[(size_t)row * N + col] = f2bf(o);
                } else {
                    o += bias[col];
                    Cf[(size_t)row * N + col] = o;
                }
            }
        }
    }
}

// ---------------- depthwise causal conv (K=4) + bias + SiLU, bf16 in/out ----------------
__global__ __launch_bounds__(256) void conv_k(const u16* __restrict__ xm,
                                              const float* __restrict__ w,
                                              const float* __restrict__ cb,
                                              u16* __restrict__ cact) {
    int idx = blockIdx.x * 256 + threadIdx.x;
    int r = idx >> 8;
    int c = (idx & 255) * 4;
    int t = r & 1023;
    const u16* base = xm + (size_t)(r - t) * I_DIM;
    float4 acc = *(const float4*)&cb[c];
#pragma unroll
    for (int j = 0; j < 4; j++) {
        int tt = t - 3 + j;
        if (tt >= 0) {
            short4 s = *(const short4*)&base[(size_t)tt * I_DIM + c];
            float4 wv = *(const float4*)&w[j * I_DIM + c];
            acc.x = fmaf(bf2f((u16)s.x), wv.x, acc.x);
            acc.y = fmaf(bf2f((u16)s.y), wv.y, acc.y);
            acc.z = fmaf(bf2f((u16)s.z), wv.z, acc.z);
            acc.w = fmaf(bf2f((u16)s.w), wv.w, acc.w);
        }
    }
    acc.x = acc.x / (1.f + __expf(-acc.x));
    acc.y = acc.y / (1.f + __expf(-acc.y));
    acc.z = acc.z / (1.f + __expf(-acc.z));
    acc.w = acc.w / (1.f + __expf(-acc.w));
    ushort4 o;
    o.x = f2bf(acc.x); o.y = f2bf(acc.y); o.z = f2bf(acc.z); o.w = f2bf(acc.w);
    *(ushort4*)&cact[(size_t)r * I_DIM + c] = o;
}

// ---------------- i/f gate pre-activations: 4 rows/block, weight-load reuse ----------------
__global__ __launch_bounds__(256) void gates_k(const u16* __restrict__ q,
                                               const u16* __restrict__ k,
                                               const u16* __restrict__ v,
                                               const float* __restrict__ wi,
                                               const float* __restrict__ bi,
                                               const float* __restrict__ wf,
                                               const float* __restrict__ bf,
                                               float* __restrict__ ipre,
                                               float* __restrict__ fpre) {
    int r0 = blockIdx.x * 4;
    int tid = threadIdx.x;
    float ai[4][4], af4[4][4];
#pragma unroll
    for (int r = 0; r < 4; r++)
#pragma unroll
        for (int m = 0; m < 4; m++) { ai[r][m] = 0.f; af4[r][m] = 0.f; }
#pragma unroll
    for (int part = 0; part < 3; part++) {
        const u16* src = (part == 0 ? q : (part == 1 ? k : v)) + (size_t)r0 * I_DIM;
        const float* wip = wi + part * I_DIM * 4;
        const float* wfp = wf + part * I_DIM * 4;
#pragma unroll
        for (int jj = 0; jj < 4; jj++) {
            int e = tid + jj * 256;
            float4 w4  = *(const float4*)&wip[e * 4];
            float4 f4v = *(const float4*)&wfp[e * 4];
#pragma unroll
            for (int r = 0; r < 4; r++) {
                float xv = bf2f(src[(size_t)r * I_DIM + e]);
                ai[r][0] = fmaf(xv, w4.x, ai[r][0]);
                ai[r][1] = fmaf(xv, w4.y, ai[r][1]);
                ai[r][2] = fmaf(xv, w4.z, ai[r][2]);
                ai[r][3] = fmaf(xv, w4.w, ai[r][3]);
                af4[r][0] = fmaf(xv, f4v.x, af4[r][0]);
                af4[r][1] = fmaf(xv, f4v.y, af4[r][1]);
                af4[r][2] = fmaf(xv, f4v.z, af4[r][2]);
                af4[r][3] = fmaf(xv, f4v.w, af4[r][3]);
            }
        }
    }
#pragma unroll
    for (int off = 32; off > 0; off >>= 1) {
#pragma unroll
        for (int r = 0; r < 4; r++)
#pragma unroll
            for (int m = 0; m < 4; m++) {
                ai[r][m]  += __shfl_down(ai[r][m], off);
                af4[r][m] += __shfl_down(af4[r][m], off);
            }
    }
    __shared__ float red[4][32];
    int wv_ = tid >> 6, lane = tid & 63;
    if (lane == 0) {
#pragma unroll
        for (int r = 0; r < 4; r++)
#pragma unroll
            for (int m = 0; m < 4; m++) {
                red[wv_][r * 8 + m]     = ai[r][m];
                red[wv_][r * 8 + 4 + m] = af4[r][m];
            }
    }
    __syncthreads();
    if (tid < 32) {
        int r = tid >> 3, m = tid & 7;
        float s_ = red[0][tid] + red[1][tid] + red[2][tid] + red[3][tid];
        int row = r0 + r, bb = row >> 10, ss = row & 1023;
        if (m < 4) ipre[((size_t)(bb * 4 + m)) * 1024 + ss] = s_ + bi[m];
        else       fpre[((size_t)(bb * 4 + (m - 4))) * 1024 + ss] = s_ + bf[m - 4];
    }
}

// ---------------- parallel scan per (b,h) ----------------
__global__ __launch_bounds__(1024) void scan_k(const float* __restrict__ ipre,
                                               const float* __restrict__ fpre,
                                               float* __restrict__ cA,
                                               float* __restrict__ MA,
                                               float* __restrict__ nF) {
    __shared__ float buf[1024];
    int bh = blockIdx.x, t = threadIdx.x;
    size_t base = (size_t)bh * 1024;
    float fp = fpre[base + t];
    float lf = (fp >= 0.f) ? -log1pf(expf(-fp)) : (fp - log1pf(expf(fp)));
    buf[t] = lf; __syncthreads();
    for (int off = 1; off < 1024; off <<= 1) {
        float u = (t >= off) ? buf[t - off] : 0.f;
        __syncthreads();
        buf[t] += u;
        __syncthreads();
    }
    float lfc = buf[t];
    float c = ipre[base + t] - lfc;
    __syncthreads();
    buf[t] = c; __syncthreads();
    for (int off = 1; off < 1024; off <<= 1) {
        float u = (t >= off) ? buf[t - off] : -3.4e38f;
        __syncthreads();
        buf[t] = fmaxf(buf[t], u);
        __syncthreads();
    }
    float M = buf[t];
    cA[base + t] = c * 1.44269504f;
    MA[base + t] = M * 1.44269504f;
    nF[base + t] = expf(-(lfc + M));
}

// ---------------- MFMA causal mLSTM attention + groupnorm + gating ----------------
// grid (16, H, B), block 256 (4 waves). t-tile 64, s-tile 32.
// 2-phase pipeline: stage(st+1) -> QK+Ps -> lgkm+bar -> PV -> vm0+bar.
__global__ __launch_bounds__(256) void attn_k(
    const u16* __restrict__ qg, const u16* __restrict__ kg, const u16* __restrict__ vt,
    const float* __restrict__ c2A, const float* __restrict__ M2A, const float* __restrict__ nFl,
    const u16* __restrict__ cact, const float* __restrict__ zb, u16* __restrict__ hb,
    const float* __restrict__ gng, const float* __restrict__ skip)
{
    __shared__ __align__(16) u16 Kb[2][32 * 256];   // [s-row][512B], chunk-swizzled
    __shared__ __align__(16) u16 Vb[2][256 * 32];   // [d-row][64B], pair-swizzled
    __shared__ __align__(16) u16 Ps[64 * 40];
    __shared__ float rsI[64];
    __shared__ float gS[64 * 4];
    __shared__ float gQ[64 * 4];
    __shared__ float gmu[64], gvr[64];

    int tid = threadIdx.x;
    int w = tid >> 6, l = tid & 63;
    int lm = l & 15, lk = l >> 4;
    int b = blockIdx.z, h = blockIdx.y;
    int T0 = blockIdx.x * 64;
    int bh32 = b * H_NUM + h;
    size_t bh = (size_t)bh32 * S_LEN;

    // Q A-fragments hoisted
    bf16x8 qf[8];
    {
        size_t base = ((size_t)(b * S_LEN + T0 + w * 16 + lm)) * I_DIM + h * DH_ + lk * 8;
#pragma unroll
        for (int ks = 0; ks < 8; ks++) qf[ks] = *(const bf16x8*)&qg[base + ks * 32];
    }
    f32x4 acc[4][4];
#pragma unroll
    for (int i = 0; i < 4; i++)
#pragma unroll
        for (int jd = 0; jd < 4; jd++) acc[i][jd] = (f32x4){0.f, 0.f, 0.f, 0.f};
    float rsum[2][4] = {{0,0,0,0},{0,0,0,0}};
    float m2r[4]; int tg[4];
#pragma unroll
    for (int q = 0; q < 4; q++) {
        tg[q] = T0 + w * 16 + lk * 4 + q;
        m2r[q] = M2A[bh + tg[q]];
    }

    const size_t krow0 = ((size_t)(b * S_LEN)) * I_DIM + h * DH_;
    const size_t vrow0 = (size_t)bh32 * 256 * S_LEN;

    auto stage = [&](int s0, int bs) {
#pragma unroll
        for (int r = 0; r < 4; r++) {
            int q = r * 256 + tid;          // K slot (16B units)
            int row = q >> 5, cl = q & 31;
            int cs = cl ^ (row & 7);
            const u16* src = kg + krow0 + (size_t)(s0 + row) * I_DIM + cs * 8;
            __builtin_amdgcn_global_load_lds((const GLOBAL_AS unsigned int*)src,
                                             (LDS_AS unsigned int*)&Kb[bs][q * 8], 16, 0, 0);
        }
#pragma unroll
        for (int r = 0; r < 4; r++) {
            int q = r * 256 + tid;          // V slot (16B units)
            int dpair = q >> 3, cp = q & 7;
            int u = cp ^ (dpair & 7);
            int d = dpair * 2 + (u >> 2), c = u & 3;
            const u16* src = vt + vrow0 + (size_t)d * S_LEN + s0 + c * 8;
            __builtin_amdgcn_global_load_lds((const GLOBAL_AS unsigned int*)src,
                                             (LDS_AS unsigned int*)&Vb[bs][q * 8], 16, 0, 0);
        }
    };

    int nst = (T0 >> 5) + 2;
    stage(0, 0);
    VM0; BAR; SFENCE;
    for (int st = 0; st < nst; st++) {
        int s0 = st * 32;
        int cur = st & 1;
        if (st + 1 < nst) stage(s0 + 32, cur ^ 1);
        // ---- QK^T from Kb[cur] ----
        f32x4 sacc[2];
        sacc[0] = (f32x4){0.f,0.f,0.f,0.f};
        sacc[1] = (f32x4){0.f,0.f,0.f,0.f};
        __builtin_amdgcn_s_setprio(1);
#pragma unroll
        for (int ks = 0; ks < 8; ks++) {
#pragma unroll
            for (int js = 0; js < 2; js++) {
                int row = js * 16 + lm;
                int ch = (ks * 4 + lk) ^ (row & 7);
                bf16x8 kf = *(const bf16x8*)&Kb[cur][row * 256 + ch * 8];
                sacc[js] = __builtin_amdgcn_mfma_f32_16x16x32_bf16(qf[ks], kf, sacc[js], 0, 0, 0);
            }
        }
        __builtin_amdgcn_s_setprio(0);
        // ---- scale, mask, round, rowsum, stage P ----
#pragma unroll
        for (int js = 0; js < 2; js++) {
            int sg = s0 + js * 16 + lm;
            float c2 = c2A[bh + sg];
#pragma unroll
            for (int q = 0; q < 4; q++) {
                float v = sacc[js][q] * 0.0625f * exp2f(c2 - m2r[q]);
                v = (sg <= tg[q]) ? v : 0.f;
                u16 pb = f2bf(v);
                rsum[js][q] += bf2f(pb);
                Ps[(w * 16 + lk * 4 + q) * 40 + js * 16 + lm] = pb;
            }
        }
        LGKM0; BAR; SFENCE;   // Ps visible to all waves
        // ---- PV from Ps + Vb[cur] ----
        bf16x8 vf[4];
#pragma unroll
        for (int jd = 0; jd < 4; jd++) {
            int d = w * 64 + jd * 16 + lm;
            int cp = (((d & 1) << 2) + lk) ^ ((d >> 1) & 7);
            vf[jd] = *(const bf16x8*)&Vb[cur][((d >> 1) * 8 + cp) * 8];
        }
        __builtin_amdgcn_s_setprio(1);
#pragma unroll
        for (int i = 0; i < 4; i++) {
            bf16x8 pa = *(const bf16x8*)&Ps[(i * 16 + lm) * 40 + lk * 8];
#pragma unroll
            for (int jd = 0; jd < 4; jd++)
                acc[i][jd] = __builtin_amdgcn_mfma_f32_16x16x32_bf16(pa, vf[jd], acc[i][jd], 0, 0, 0);
        }
        __builtin_amdgcn_s_setprio(0);
        VM0; BAR; SFENCE;     // stage(st+1) landed; Kb/Vb/Ps free
    }
    // ---- rowsum reduce ----
    {
        float rq[4];
#pragma unroll
        for (int q = 0; q < 4; q++) rq[q] = rsum[0][q] + rsum[1][q];
#pragma unroll
        for (int m = 1; m < 16; m <<= 1) {
#pragma unroll
            for (int q = 0; q < 4; q++) rq[q] += __shfl_xor(rq[q], m);
        }
        if (lm == 0) {
#pragma unroll
            for (int q = 0; q < 4; q++) rsI[w * 16 + lk * 4 + q] = rq[q];
        }
    }
    __syncthreads();
    if (tid < 64) {
        float n = fmaxf(fabsf(rsI[tid]), nFl[bh + T0 + tid]);
        rsI[tid] = 1.f / n;
    }
    __syncthreads();
    // ---- normalize + groupnorm stats ----
#pragma unroll
    for (int i = 0; i < 4; i++) {
#pragma unroll
        for (int q = 0; q < 4; q++) {
            int rl = i * 16 + lk * 4 + q;
            float inv = rsI[rl];
            float ps = 0.f, pq = 0.f;
#pragma unroll
            for (int jd = 0; jd < 4; jd++) {
                float v = acc[i][jd][q] * inv;
                acc[i][jd][q] = v;
                ps += v; pq += v * v;
            }
#pragma unroll
            for (int m = 1; m < 16; m <<= 1) {
                ps += __shfl_xor(ps, m);
                pq += __shfl_xor(pq, m);
            }
            if (lm == 0) { gS[rl * 4 + w] = ps; gQ[rl * 4 + w] = pq; }
        }
    }
    __syncthreads();
    if (tid < 64) {
        float s1 = gS[tid*4] + gS[tid*4+1] + gS[tid*4+2] + gS[tid*4+3];
        float s2 = gQ[tid*4] + gQ[tid*4+1] + gQ[tid*4+2] + gQ[tid*4+3];
        float mu = s1 * (1.f / 256.f);
        float var = s2 * (1.f / 256.f) - mu * mu;
        gmu[tid] = mu;
        gvr[tid] = rsqrtf(var + 1e-5f);
    }
    __syncthreads();
    // ---- epilogue ----
#pragma unroll
    for (int i = 0; i < 4; i++) {
#pragma unroll
        for (int q = 0; q < 4; q++) {
            int rl = i * 16 + lk * 4 + q;
            size_t r = (size_t)b * S_LEN + T0 + rl;
            float mu = gmu[rl], rv = gvr[rl];
#pragma unroll
            for (int jd = 0; jd < 4; jd++) {
                int cix = h * DH_ + w * 64 + jd * 16 + lm;
                float val = (acc[i][jd][q] - mu) * rv * gng[cix];
                float ca = bf2f(cact[r * I_DIM + cix]);
                float z = zb[r * I_DIM + cix];
                float hm = (val + skip[cix] * ca) * (z / (1.f + __expf(-z)));
                hb[r * I_DIM + cix] = f2bf(hm);
            }
        }
    }
}

// ---------------- host launch ----------------
extern "C" void kernel_launch(void* const* d_in, const int* in_sizes, int n_in,
                              void* d_out, int out_size, void* d_ws, size_t ws_size,
                              hipStream_t stream) {
    const float* x      = (const float*)d_in[0];
    const float* ln_g   = (const float*)d_in[1];
    const float* ln_b   = (const float*)d_in[2];
    const float* w_up   = (const float*)d_in[3];
    const float* conv_w = (const float*)d_in[4];
    const float* conv_b = (const float*)d_in[5];
    const float* wq     = (const float*)d_in[6];
    const float* wk     = (const float*)d_in[7];
    const float* wv     = (const float*)d_in[8];
    const float* w_i    = (const float*)d_in[9];
    const float* b_i    = (const float*)d_in[10];
    const float* w_f    = (const float*)d_in[11];
    const float* b_f    = (const float*)d_in[12];
    const float* skip   = (const float*)d_in[13];
    const float* gn_g   = (const float*)d_in[14];
    const float* w_down = (const float*)d_in[15];
    const float* b_down = (const float*)d_in[16];
    const float* w_fin  = (const float*)d_in[17];
    const float* b_fin  = (const float*)d_in[18];

    char* p = (char*)d_ws;
    auto alloc = [&](size_t bytes) { void* r = p; p += (bytes + 255) & ~(size_t)255; return r; };
    float* zbuf  = (float*)alloc((size_t)ROWS * 1024 * 4);
    float* xa    = (float*)alloc((size_t)ROWS * 512 * 4);
    float* xb2   = (float*)alloc((size_t)ROWS * 512 * 4);
    u16*  xln    = (u16*)alloc((size_t)ROWS * 512 * 2);
    u16*  xm     = (u16*)alloc((size_t)ROWS * 1024 * 2);
    u16*  cactb  = (u16*)alloc((size_t)ROWS * 1024 * 2);
    u16*  qbf    = (u16*)alloc((size_t)ROWS * 1024 * 2);
    u16*  kbf    = (u16*)alloc((size_t)ROWS * 1024 * 2);
    u16*  vbf    = (u16*)alloc((size_t)ROWS * 1024 * 2);
    u16*  vtg    = (u16*)alloc((size_t)32 * 256 * 1024 * 2);
    u16*  hbf    = (u16*)alloc((size_t)ROWS * 1024 * 2);
    u16*  xoutb  = (u16*)alloc((size_t)ROWS * 512 * 2);
    u16*  wupT   = (u16*)alloc((size_t)2 * 2048 * 512 * 2);
    u16*  wqT    = (u16*)alloc((size_t)2 * 1024 * 1024 * 2);
    u16*  wkT    = (u16*)alloc((size_t)2 * 1024 * 1024 * 2);
    u16*  wvT    = (u16*)alloc((size_t)2 * 1024 * 1024 * 2);
    u16*  wdT    = (u16*)alloc((size_t)2 * 512 * 1024 * 2);
    u16*  wfT    = (u16*)alloc((size_t)128 * 512 * 2);
    float* ipre  = (float*)alloc(32768 * 4);
    float* fpre  = (float*)alloc(32768 * 4);
    float* cA    = (float*)alloc(32768 * 4);
    float* MA    = (float*)alloc(32768 * 4);
    float* nF    = (float*)alloc(32768 * 4);

    for (int l = 0; l < 2; l++) {
        cvtT_k<<<dim3(16, 64), 256, 0, stream>>>(w_up + (size_t)l * 512 * 2048, wupT + (size_t)l * 2048 * 512, 512, 2048);
        cvtT_k<<<dim3(32, 32), 256, 0, stream>>>(wq + (size_t)l * 1024 * 1024, wqT + (size_t)l * 1024 * 1024, 1024, 1024);
        cvtT_k<<<dim3(32, 32), 256, 0, stream>>>(wk + (size_t)l * 1024 * 1024, wkT + (size_t)l * 1024 * 1024, 1024, 1024);
        cvtT_k<<<dim3(32, 32), 256, 0, stream>>>(wv + (size_t)l * 1024 * 1024, wvT + (size_t)l * 1024 * 1024, 1024, 1024);
        cvtT_k<<<dim3(32, 16), 256, 0, stream>>>(w_down + (size_t)l * 1024 * 512, wdT + (size_t)l * 512 * 1024, 1024, 512);
    }
    cvtT_k<<<dim3(16, 4), 256, 0, stream>>>(w_fin, wfT, 512, 128);

    const float* xin = x;
    for (int l = 0; l < 2; l++) {
        float* xout = (l == 0) ? xa : xb2;
        ln_fused_k<<<ROWS, 64, 0, stream>>>(xin, ln_g + l * 512, ln_b + l * 512, xln);
        gemm_bf16_k<1><<<dim3(16, 64), 256, 0, stream>>>(
            xln, wupT + (size_t)l * 2048 * 512, 2048, 512, zbuf, xm, nullptr, nullptr, 0);
        conv_k<<<ROWS, 256, 0, stream>>>(xm, conv_w + l * 4 * I_DIM, conv_b + l * I_DIM, cactb);
        gemm_bf16_k<0><<<dim3(8, 64), 256, 0, stream>>>(
            xm, wvT + (size_t)l * 1024 * 1024, 1024, 1024, nullptr, vbf, nullptr, nullptr, 0);
        gemm_bf16_k<0><<<dim3(8, 64), 256, 0, stream>>>(
            cactb, wqT + (size_t)l * 1024 * 1024, 1024, 1024, nullptr, qbf, nullptr, nullptr, 0);
        gemm_bf16_k<0><<<dim3(8, 64), 256, 0, stream>>>(
            cactb, wkT + (size_t)l * 1024 * 1024, 1024, 1024, nullptr, kbf, nullptr, nullptr, 0);
        vt_k<<<dim3(32, 8, 32), 256, 0, stream>>>(vbf, vtg);
        gates_k<<<ROWS / 4, 256, 0, stream>>>(qbf, kbf, vbf,
            w_i + l * 3072 * 4, b_i + l * 4, w_f + l * 3072 * 4, b_f + l * 4, ipre, fpre);
        scan_k<<<32, 1024, 0, stream>>>(ipre, fpre, cA, MA, nF);
        attn_k<<<dim3(16, 4, 8), 256, 0, stream>>>(qbf, kbf, vtg, cA, MA, nF, cactb, zbuf, hbf,
            gn_g + l * I_DIM, skip + l * I_DIM);
        gemm_bf16_k<2><<<dim3(4, 64), 256, 0, stream>>>(
            hbf, wdT + (size_t)l * 512 * 1024, 512, 1024, xout, xoutb,
            b_down + l * 512, xin, 512);
        xin = xout;
    }
    gemm_bf16_k<3><<<dim3(1, 64), 256, 0, stream>>>(
        xoutb, wfT, 128, 512, (float*)d_out, nullptr, b_fin, nullptr, 0);
}

// Round 6
// 693.918 us; speedup vs baseline: 7.1999x; 1.0037x over previous
//
#include <hip/hip_runtime.h>
#include <math.h>

#define S_LEN 1024
#define I_DIM 1024
#define DH_   256
#define H_NUM 4
#define B_NUM 8
#define ROWS  (B_NUM*S_LEN)   // 8192

#define GLOBAL_AS __attribute__((address_space(1)))
#define LDS_AS    __attribute__((address_space(3)))

#define VM0    asm volatile("s_waitcnt vmcnt(0)" ::: "memory")
#define LGKM0  asm volatile("s_waitcnt lgkmcnt(0)" ::: "memory")
#define BAR    __builtin_amdgcn_s_barrier()
#define SFENCE __builtin_amdgcn_sched_barrier(0)

typedef __attribute__((ext_vector_type(8))) short bf16x8;
typedef __attribute__((ext_vector_type(4))) float f32x4;
typedef unsigned short u16;

__device__ __forceinline__ u16 f2bf(float f) {
    union { float f; unsigned u; } v; v.f = f;
    unsigned r = v.u + 0x7FFF + ((v.u >> 16) & 1);
    return (u16)(r >> 16);
}
__device__ __forceinline__ float bf2f(u16 h) {
    union { unsigned u; float f; } v; v.u = ((unsigned)h) << 16;
    return v.f;
}

// ---------------- fused LayerNorm -> bf16 ----------------
__global__ __launch_bounds__(64) void ln_fused_k(const float* __restrict__ x,
                                                 const float* __restrict__ g,
                                                 const float* __restrict__ b,
                                                 u16* __restrict__ out) {
    int row = blockIdx.x, lane = threadIdx.x;
    const float* xr = x + (size_t)row * 512;
    float4 a = *(const float4*)&xr[lane * 8];
    float4 c = *(const float4*)&xr[lane * 8 + 4];
    float s  = a.x + a.y + a.z + a.w + c.x + c.y + c.z + c.w;
    float s2 = a.x*a.x + a.y*a.y + a.z*a.z + a.w*a.w
             + c.x*c.x + c.y*c.y + c.z*c.z + c.w*c.w;
#pragma unroll
    for (int off = 32; off > 0; off >>= 1) {
        s  += __shfl_down(s, off);
        s2 += __shfl_down(s2, off);
    }
    s = __shfl(s, 0); s2 = __shfl(s2, 0);
    float mu = s * (1.f / 512.f);
    float rstd = rsqrtf(s2 * (1.f / 512.f) - mu * mu + 1e-5f);
    int e0 = lane * 8;
    float y[8] = {a.x,a.y,a.z,a.w,c.x,c.y,c.z,c.w};
    ushort4 o0, o1;
    o0.x = f2bf((y[0]-mu)*rstd*g[e0+0]+b[e0+0]);
    o0.y = f2bf((y[1]-mu)*rstd*g[e0+1]+b[e0+1]);
    o0.z = f2bf((y[2]-mu)*rstd*g[e0+2]+b[e0+2]);
    o0.w = f2bf((y[3]-mu)*rstd*g[e0+3]+b[e0+3]);
    o1.x = f2bf((y[4]-mu)*rstd*g[e0+4]+b[e0+4]);
    o1.y = f2bf((y[5]-mu)*rstd*g[e0+5]+b[e0+5]);
    o1.z = f2bf((y[6]-mu)*rstd*g[e0+6]+b[e0+6]);
    o1.w = f2bf((y[7]-mu)*rstd*g[e0+7]+b[e0+7]);
    *(ushort4*)&out[(size_t)row * 512 + e0]     = o0;
    *(ushort4*)&out[(size_t)row * 512 + e0 + 4] = o1;
}

// ---------------- weight transpose + cvt: Wt[n][k] = bf16(W[k][n]) ----------------
__global__ __launch_bounds__(256) void cvtT_k(const float* __restrict__ W,
                                              u16* __restrict__ Wt, int K, int N) {
    __shared__ float t[32][33];
    int k0 = blockIdx.x * 32, n0 = blockIdx.y * 32;
    int c = threadIdx.x & 31, r8 = threadIdx.x >> 5;
#pragma unroll
    for (int q = 0; q < 4; q++) {
        int r = r8 * 4 + q;
        t[r][c] = W[(size_t)(k0 + r) * N + n0 + c];
    }
    __syncthreads();
#pragma unroll
    for (int q = 0; q < 4; q++) {
        int r = r8 * 4 + q;
        Wt[(size_t)(n0 + r) * K + k0 + c] = f2bf(t[c][r]);
    }
}

// ---------------- V transpose: vt[bh][d][s] = v[b*S+s][h*256+d] ----------------
__global__ __launch_bounds__(256) void vt_k(const u16* __restrict__ v,
                                            u16* __restrict__ vt) {
    __shared__ u16 t[32][34];
    int s0 = blockIdx.x * 32, d0 = blockIdx.y * 32, bh = blockIdx.z;
    int b = bh >> 2, h = bh & 3;
    int c = threadIdx.x & 31, r4 = threadIdx.x >> 5;
#pragma unroll
    for (int q = 0; q < 4; q++) {
        int r = r4 * 4 + q;
        t[r][c] = v[(size_t)(b * 1024 + s0 + r) * I_DIM + h * 256 + d0 + c];
    }
    __syncthreads();
#pragma unroll
    for (int q = 0; q < 4; q++) {
        int r = r4 * 4 + q;
        vt[((size_t)bh * 256 + d0 + r) * 1024 + s0 + c] = t[c][r];
    }
}

// ---------------- bf16 MFMA GEMM, 2-phase dbuf + XCD swizzle ----------------
template<int EPI>
__global__ __launch_bounds__(256) void gemm_bf16_k(
    const u16* __restrict__ A, const u16* __restrict__ Wt, int N, int K,
    float* __restrict__ Cf, u16* __restrict__ Cb,
    const float* __restrict__ bias, const float* __restrict__ res, int ldres)
{
    __shared__ __align__(16) u16 As[2][128 * 32];
    __shared__ __align__(16) u16 Bs[2][128 * 32];
    int tid = threadIdx.x;
    int lane = tid & 63;
    int wm = (tid >> 6) & 1, wn = tid >> 7;
    int gx = gridDim.x;
    int nwg = gx * gridDim.y;
    int bid = blockIdx.y * gx + blockIdx.x;
    int cpx = nwg >> 3;
    int swz = (bid & 7) * cpx + (bid >> 3);
    int r0 = (swz / gx) * 128, n0 = (swz % gx) * 128;

    int arow = tid >> 2, acol = (tid & 3) * 8;
    const u16* ap0 = A  + (size_t)(r0 + arow) * K + acol;
    const u16* ap1 = A  + (size_t)(r0 + 64 + arow) * K + acol;
    const u16* bp0 = Wt + (size_t)(n0 + arow) * K + acol;
    const u16* bp1 = Wt + (size_t)(n0 + 64 + arow) * K + acol;

    auto stage = [&](int kt, int bs) {
        int koff = kt * 32;
        __builtin_amdgcn_global_load_lds((const GLOBAL_AS unsigned int*)(ap0 + koff), (LDS_AS unsigned int*)&As[bs][tid * 8], 16, 0, 0);
        __builtin_amdgcn_global_load_lds((const GLOBAL_AS unsigned int*)(ap1 + koff), (LDS_AS unsigned int*)&As[bs][2048 + tid * 8], 16, 0, 0);
        __builtin_amdgcn_global_load_lds((const GLOBAL_AS unsigned int*)(bp0 + koff), (LDS_AS unsigned int*)&Bs[bs][tid * 8], 16, 0, 0);
        __builtin_amdgcn_global_load_lds((const GLOBAL_AS unsigned int*)(bp1 + koff), (LDS_AS unsigned int*)&Bs[bs][2048 + tid * 8], 16, 0, 0);
    };

    f32x4 acc[4][4];
#pragma unroll
    for (int i = 0; i < 4; i++)
#pragma unroll
        for (int j = 0; j < 4; j++) acc[i][j] = (f32x4){0.f, 0.f, 0.f, 0.f};

    int lm = lane & 15, lk = (lane >> 4) * 8;
    int nt = K >> 5;
    stage(0, 0);
    VM0; BAR; SFENCE;
    for (int t = 0; t < nt; ++t) {
        int cur = t & 1;
        if (t + 1 < nt) stage(t + 1, cur ^ 1);
        bf16x8 af[4], bfr[4];
#pragma unroll
        for (int f = 0; f < 4; f++) {
            af[f]  = *(const bf16x8*)&As[cur][(wm * 64 + f * 16 + lm) * 32 + lk];
            bfr[f] = *(const bf16x8*)&Bs[cur][(wn * 64 + f * 16 + lm) * 32 + lk];
        }
#pragma unroll
        for (int i = 0; i < 4; i++)
#pragma unroll
            for (int j = 0; j < 4; j++)
                acc[i][j] = __builtin_amdgcn_mfma_f32_16x16x32_bf16(af[i], bfr[j], acc[i][j], 0, 0, 0);
        VM0; BAR; SFENCE;
    }
    int lr = (lane >> 4) * 4;
#pragma unroll
    for (int i = 0; i < 4; i++) {
#pragma unroll
        for (int j = 0; j < 4; j++) {
#pragma unroll
            for (int q = 0; q < 4; q++) {
                int row = r0 + wm * 64 + i * 16 + lr + q;
                int col = n0 + wn * 64 + j * 16 + lm;
                float o = acc[i][j][q];
                if (EPI == 0) {
                    Cb[(size_t)row * N + col] = f2bf(o);
                } else if (EPI == 1) {
                    if (col < 1024) Cb[(size_t)row * 1024 + col] = f2bf(o);
                    else            Cf[(size_t)row * 1024 + (col - 1024)] = o;
                } else if (EPI == 2) {
                    o += bias[col] + res[(size_t)row * ldres + col];
                    Cf[(size_t)row * N + col] = o;
                    Cb[(size_t)row * N + col] = f2bf(o);
                } else {
                    o += bias[col];
                    Cf[(size_t)row * N + col] = o;
                }
            }
        }
    }
}

// ---------------- depthwise causal conv (K=4) + bias + SiLU, bf16 in/out ----------------
__global__ __launch_bounds__(256) void conv_k(const u16* __restrict__ xm,
                                              const float* __restrict__ w,
                                              const float* __restrict__ cb,
                                              u16* __restrict__ cact) {
    int idx = blockIdx.x * 256 + threadIdx.x;
    int r = idx >> 8;
    int c = (idx & 255) * 4;
    int t = r & 1023;
    const u16* base = xm + (size_t)(r - t) * I_DIM;
    float4 acc = *(const float4*)&cb[c];
#pragma unroll
    for (int j = 0; j < 4; j++) {
        int tt = t - 3 + j;
        if (tt >= 0) {
            short4 s = *(const short4*)&base[(size_t)tt * I_DIM + c];
            float4 wv = *(const float4*)&w[j * I_DIM + c];
            acc.x = fmaf(bf2f((u16)s.x), wv.x, acc.x);
            acc.y = fmaf(bf2f((u16)s.y), wv.y, acc.y);
            acc.z = fmaf(bf2f((u16)s.z), wv.z, acc.z);
            acc.w = fmaf(bf2f((u16)s.w), wv.w, acc.w);
        }
    }
    acc.x = acc.x / (1.f + __expf(-acc.x));
    acc.y = acc.y / (1.f + __expf(-acc.y));
    acc.z = acc.z / (1.f + __expf(-acc.z));
    acc.w = acc.w / (1.f + __expf(-acc.w));
    ushort4 o;
    o.x = f2bf(acc.x); o.y = f2bf(acc.y); o.z = f2bf(acc.z); o.w = f2bf(acc.w);
    *(ushort4*)&cact[(size_t)r * I_DIM + c] = o;
}

// ---------------- i/f gate pre-activations: 4 rows/block, weight-load reuse ----------------
__global__ __launch_bounds__(256) void gates_k(const u16* __restrict__ q,
                                               const u16* __restrict__ k,
                                               const u16* __restrict__ v,
                                               const float* __restrict__ wi,
                                               const float* __restrict__ bi,
                                               const float* __restrict__ wf,
                                               const float* __restrict__ bf,
                                               float* __restrict__ ipre,
                                               float* __restrict__ fpre) {
    int r0 = blockIdx.x * 4;
    int tid = threadIdx.x;
    float ai[4][4], af4[4][4];
#pragma unroll
    for (int r = 0; r < 4; r++)
#pragma unroll
        for (int m = 0; m < 4; m++) { ai[r][m] = 0.f; af4[r][m] = 0.f; }
#pragma unroll
    for (int part = 0; part < 3; part++) {
        const u16* src = (part == 0 ? q : (part == 1 ? k : v)) + (size_t)r0 * I_DIM;
        const float* wip = wi + part * I_DIM * 4;
        const float* wfp = wf + part * I_DIM * 4;
#pragma unroll
        for (int jj = 0; jj < 4; jj++) {
            int e = tid + jj * 256;
            float4 w4  = *(const float4*)&wip[e * 4];
            float4 f4v = *(const float4*)&wfp[e * 4];
#pragma unroll
            for (int r = 0; r < 4; r++) {
                float xv = bf2f(src[(size_t)r * I_DIM + e]);
                ai[r][0] = fmaf(xv, w4.x, ai[r][0]);
                ai[r][1] = fmaf(xv, w4.y, ai[r][1]);
                ai[r][2] = fmaf(xv, w4.z, ai[r][2]);
                ai[r][3] = fmaf(xv, w4.w, ai[r][3]);
                af4[r][0] = fmaf(xv, f4v.x, af4[r][0]);
                af4[r][1] = fmaf(xv, f4v.y, af4[r][1]);
                af4[r][2] = fmaf(xv, f4v.z, af4[r][2]);
                af4[r][3] = fmaf(xv, f4v.w, af4[r][3]);
            }
        }
    }
#pragma unroll
    for (int off = 32; off > 0; off >>= 1) {
#pragma unroll
        for (int r = 0; r < 4; r++)
#pragma unroll
            for (int m = 0; m < 4; m++) {
                ai[r][m]  += __shfl_down(ai[r][m], off);
                af4[r][m] += __shfl_down(af4[r][m], off);
            }
    }
    __shared__ float red[4][32];
    int wv_ = tid >> 6, lane = tid & 63;
    if (lane == 0) {
#pragma unroll
        for (int r = 0; r < 4; r++)
#pragma unroll
            for (int m = 0; m < 4; m++) {
                red[wv_][r * 8 + m]     = ai[r][m];
                red[wv_][r * 8 + 4 + m] = af4[r][m];
            }
    }
    __syncthreads();
    if (tid < 32) {
        int r = tid >> 3, m = tid & 7;
        float s_ = red[0][tid] + red[1][tid] + red[2][tid] + red[3][tid];
        int row = r0 + r, bb = row >> 10, ss = row & 1023;
        if (m < 4) ipre[((size_t)(bb * 4 + m)) * 1024 + ss] = s_ + bi[m];
        else       fpre[((size_t)(bb * 4 + (m - 4))) * 1024 + ss] = s_ + bf[m - 4];
    }
}

// ---------------- parallel scan per (b,h) ----------------
__global__ __launch_bounds__(1024) void scan_k(const float* __restrict__ ipre,
                                               const float* __restrict__ fpre,
                                               float* __restrict__ cA,
                                               float* __restrict__ MA,
                                               float* __restrict__ nF) {
    __shared__ float buf[1024];
    int bh = blockIdx.x, t = threadIdx.x;
    size_t base = (size_t)bh * 1024;
    float fp = fpre[base + t];
    float lf = (fp >= 0.f) ? -log1pf(expf(-fp)) : (fp - log1pf(expf(fp)));
    buf[t] = lf; __syncthreads();
    for (int off = 1; off < 1024; off <<= 1) {
        float u = (t >= off) ? buf[t - off] : 0.f;
        __syncthreads();
        buf[t] += u;
        __syncthreads();
    }
    float lfc = buf[t];
    float c = ipre[base + t] - lfc;
    __syncthreads();
    buf[t] = c; __syncthreads();
    for (int off = 1; off < 1024; off <<= 1) {
        float u = (t >= off) ? buf[t - off] : -3.4e38f;
        __syncthreads();
        buf[t] = fmaxf(buf[t], u);
        __syncthreads();
    }
    float M = buf[t];
    cA[base + t] = c * 1.44269504f;
    MA[base + t] = M * 1.44269504f;
    nF[base + t] = expf(-(lfc + M));
}

// ---------------- MFMA causal mLSTM attention + groupnorm + gating ----------------
// grid (16, H, B), block 256 (4 waves). t-tile 64 (LPT-reversed), s-tile 32.
// K LDS double-buffered (gload_lds); V + c2 register-prefetched one tile ahead.
__global__ __launch_bounds__(256) void attn_k(
    const u16* __restrict__ qg, const u16* __restrict__ kg, const u16* __restrict__ vt,
    const float* __restrict__ c2A, const float* __restrict__ M2A, const float* __restrict__ nFl,
    const u16* __restrict__ cact, const float* __restrict__ zb, u16* __restrict__ hb,
    const float* __restrict__ gng, const float* __restrict__ skip)
{
    __shared__ __align__(16) u16 Kb[2][32 * 256];   // [s-row][512B], chunk-swizzled
    __shared__ __align__(16) u16 Ps[64 * 40];
    __shared__ float rsI[64];
    __shared__ float gS[64 * 4];
    __shared__ float gQ[64 * 4];
    __shared__ float gmu[64], gvr[64];

    int tid = threadIdx.x;
    int w = tid >> 6, l = tid & 63;
    int lm = l & 15, lk = l >> 4;
    int b = blockIdx.z, h = blockIdx.y;
    int T0 = (15 - blockIdx.x) * 64;      // LPT: longest blocks first
    int bh32 = b * H_NUM + h;
    size_t bh = (size_t)bh32 * S_LEN;

    // Q A-fragments hoisted
    bf16x8 qf[8];
    {
        size_t base = ((size_t)(b * S_LEN + T0 + w * 16 + lm)) * I_DIM + h * DH_ + lk * 8;
#pragma unroll
        for (int ks = 0; ks < 8; ks++) qf[ks] = *(const bf16x8*)&qg[base + ks * 32];
    }
    f32x4 acc[4][4];
#pragma unroll
    for (int i = 0; i < 4; i++)
#pragma unroll
        for (int jd = 0; jd < 4; jd++) acc[i][jd] = (f32x4){0.f, 0.f, 0.f, 0.f};
    float rsum[2][4] = {{0,0,0,0},{0,0,0,0}};
    float m2r[4]; int tg[4];
#pragma unroll
    for (int q = 0; q < 4; q++) {
        tg[q] = T0 + w * 16 + lk * 4 + q;
        m2r[q] = M2A[bh + tg[q]];
    }

    const size_t krow0 = ((size_t)(b * S_LEN)) * I_DIM + h * DH_;
    // per-lane V^T pointer: row d = w*64 + jd*16 + lm, col s0 + lk*8
    const u16* vptr = vt + (size_t)bh32 * 256 * S_LEN + (size_t)(w * 64 + lm) * S_LEN + lk * 8;

    auto stageK = [&](int s0, int bs) {
#pragma unroll
        for (int r = 0; r < 4; r++) {
            int q = r * 256 + tid;          // 16B slot
            int row = q >> 5, cl = q & 31;
            int cs = cl ^ (row & 7);
            const u16* src = kg + krow0 + (size_t)(s0 + row) * I_DIM + cs * 8;
            __builtin_amdgcn_global_load_lds((const GLOBAL_AS unsigned int*)src,
                                             (LDS_AS unsigned int*)&Kb[bs][q * 8], 16, 0, 0);
        }
    };

    int nst = (T0 >> 5) + 2;
    // prologue: tile 0 K stage + V/c2 register loads
    stageK(0, 0);
    bf16x8 vA[4], vB[4];
    float c2c[2], c2n[2];
#pragma unroll
    for (int jd = 0; jd < 4; jd++) vA[jd] = *(const bf16x8*)(vptr + jd * 16 * S_LEN);
    c2c[0] = c2A[bh + lm];
    c2c[1] = c2A[bh + 16 + lm];
    VM0; BAR; SFENCE;

    for (int st = 0; st < nst; st++) {
        int s0 = st * 32;
        int cur = st & 1;
        int more = (st + 1 < nst);
        if (more) {
            stageK(s0 + 32, cur ^ 1);
#pragma unroll
            for (int jd = 0; jd < 4; jd++) vB[jd] = *(const bf16x8*)(vptr + jd * 16 * S_LEN + s0 + 32);
            c2n[0] = c2A[bh + s0 + 32 + lm];
            c2n[1] = c2A[bh + s0 + 48 + lm];
        }
        // ---- QK^T from Kb[cur] ----
        f32x4 sacc[2];
        sacc[0] = (f32x4){0.f,0.f,0.f,0.f};
        sacc[1] = (f32x4){0.f,0.f,0.f,0.f};
        __builtin_amdgcn_s_setprio(1);
#pragma unroll
        for (int ks = 0; ks < 8; ks++) {
#pragma unroll
            for (int js = 0; js < 2; js++) {
                int row = js * 16 + lm;
                int ch = (ks * 4 + lk) ^ (row & 7);
                bf16x8 kf = *(const bf16x8*)&Kb[cur][row * 256 + ch * 8];
                sacc[js] = __builtin_amdgcn_mfma_f32_16x16x32_bf16(qf[ks], kf, sacc[js], 0, 0, 0);
            }
        }
        __builtin_amdgcn_s_setprio(0);
        // ---- scale, mask, round, rowsum, stage P ----
#pragma unroll
        for (int js = 0; js < 2; js++) {
            int sg = s0 + js * 16 + lm;
#pragma unroll
            for (int q = 0; q < 4; q++) {
                float v = sacc[js][q] * 0.0625f * __builtin_amdgcn_exp2f(c2c[js] - m2r[q]);
                v = (sg <= tg[q]) ? v : 0.f;
                u16 pb = f2bf(v);
                rsum[js][q] += bf2f(pb);
                Ps[(w * 16 + lk * 4 + q) * 40 + js * 16 + lm] = pb;
            }
        }
        LGKM0; BAR; SFENCE;   // Ps visible to all waves
        // ---- PV from Ps + vA regs ----
        __builtin_amdgcn_s_setprio(1);
#pragma unroll
        for (int i = 0; i < 4; i++) {
            bf16x8 pa = *(const bf16x8*)&Ps[(i * 16 + lm) * 40 + lk * 8];
#pragma unroll
            for (int jd = 0; jd < 4; jd++)
                acc[i][jd] = __builtin_amdgcn_mfma_f32_16x16x32_bf16(pa, vA[jd], acc[i][jd], 0, 0, 0);
        }
        __builtin_amdgcn_s_setprio(0);
        VM0; BAR; SFENCE;     // K stage (st+1) + V/c2 regs landed; Ps free
        if (more) {
#pragma unroll
            for (int jd = 0; jd < 4; jd++) vA[jd] = vB[jd];
            c2c[0] = c2n[0]; c2c[1] = c2n[1];
        }
    }
    // ---- rowsum reduce ----
    {
        float rq[4];
#pragma unroll
        for (int q = 0; q < 4; q++) rq[q] = rsum[0][q] + rsum[1][q];
#pragma unroll
        for (int m = 1; m < 16; m <<= 1) {
#pragma unroll
            for (int q = 0; q < 4; q++) rq[q] += __shfl_xor(rq[q], m);
        }
        if (lm == 0) {
#pragma unroll
            for (int q = 0; q < 4; q++) rsI[w * 16 + lk * 4 + q] = rq[q];
        }
    }
    __syncthreads();
    if (tid < 64) {
        float n = fmaxf(fabsf(rsI[tid]), nFl[bh + T0 + tid]);
        rsI[tid] = 1.f / n;
    }
    __syncthreads();
    // ---- normalize + groupnorm stats ----
#pragma unroll
    for (int i = 0; i < 4; i++) {
#pragma unroll
        for (int q = 0; q < 4; q++) {
            int rl = i * 16 + lk * 4 + q;
            float inv = rsI[rl];
            float ps = 0.f, pq = 0.f;
#pragma unroll
            for (int jd = 0; jd < 4; jd++) {
                float v = acc[i][jd][q] * inv;
                acc[i][jd][q] = v;
                ps += v; pq += v * v;
            }
#pragma unroll
            for (int m = 1; m < 16; m <<= 1) {
                ps += __shfl_xor(ps, m);
                pq += __shfl_xor(pq, m);
            }
            if (lm == 0) { gS[rl * 4 + w] = ps; gQ[rl * 4 + w] = pq; }
        }
    }
    __syncthreads();
    if (tid < 64) {
        float s1 = gS[tid*4] + gS[tid*4+1] + gS[tid*4+2] + gS[tid*4+3];
        float s2 = gQ[tid*4] + gQ[tid*4+1] + gQ[tid*4+2] + gQ[tid*4+3];
        float mu = s1 * (1.f / 256.f);
        float var = s2 * (1.f / 256.f) - mu * mu;
        gmu[tid] = mu;
        gvr[tid] = rsqrtf(var + 1e-5f);
    }
    __syncthreads();
    // ---- epilogue ----
#pragma unroll
    for (int i = 0; i < 4; i++) {
#pragma unroll
        for (int q = 0; q < 4; q++) {
            int rl = i * 16 + lk * 4 + q;
            size_t r = (size_t)b * S_LEN + T0 + rl;
            float mu = gmu[rl], rv = gvr[rl];
#pragma unroll
            for (int jd = 0; jd < 4; jd++) {
                int cix = h * DH_ + w * 64 + jd * 16 + lm;
                float val = (acc[i][jd][q] - mu) * rv * gng[cix];
                float ca = bf2f(cact[r * I_DIM + cix]);
                float z = zb[r * I_DIM + cix];
                float hm = (val + skip[cix] * ca) * (z / (1.f + __expf(-z)));
                hb[r * I_DIM + cix] = f2bf(hm);
            }
        }
    }
}

// ---------------- host launch ----------------
extern "C" void kernel_launch(void* const* d_in, const int* in_sizes, int n_in,
                              void* d_out, int out_size, void* d_ws, size_t ws_size,
                              hipStream_t stream) {
    const float* x      = (const float*)d_in[0];
    const float* ln_g   = (const float*)d_in[1];
    const float* ln_b   = (const float*)d_in[2];
    const float* w_up   = (const float*)d_in[3];
    const float* conv_w = (const float*)d_in[4];
    const float* conv_b = (const float*)d_in[5];
    const float* wq     = (const float*)d_in[6];
    const float* wk     = (const float*)d_in[7];
    const float* wv     = (const float*)d_in[8];
    const float* w_i    = (const float*)d_in[9];
    const float* b_i    = (const float*)d_in[10];
    const float* w_f    = (const float*)d_in[11];
    const float* b_f    = (const float*)d_in[12];
    const float* skip   = (const float*)d_in[13];
    const float* gn_g   = (const float*)d_in[14];
    const float* w_down = (const float*)d_in[15];
    const float* b_down = (const float*)d_in[16];
    const float* w_fin  = (const float*)d_in[17];
    const float* b_fin  = (const float*)d_in[18];

    char* p = (char*)d_ws;
    auto alloc = [&](size_t bytes) { void* r = p; p += (bytes + 255) & ~(size_t)255; return r; };
    float* zbuf  = (float*)alloc((size_t)ROWS * 1024 * 4);
    float* xa    = (float*)alloc((size_t)ROWS * 512 * 4);
    float* xb2   = (float*)alloc((size_t)ROWS * 512 * 4);
    u16*  xln    = (u16*)alloc((size_t)ROWS * 512 * 2);
    u16*  xm     = (u16*)alloc((size_t)ROWS * 1024 * 2);
    u16*  cactb  = (u16*)alloc((size_t)ROWS * 1024 * 2);
    u16*  qbf    = (u16*)alloc((size_t)ROWS * 1024 * 2);
    u16*  kbf    = (u16*)alloc((size_t)ROWS * 1024 * 2);
    u16*  vbf    = (u16*)alloc((size_t)ROWS * 1024 * 2);
    u16*  vtg    = (u16*)alloc((size_t)32 * 256 * 1024 * 2);
    u16*  hbf    = (u16*)alloc((size_t)ROWS * 1024 * 2);
    u16*  xoutb  = (u16*)alloc((size_t)ROWS * 512 * 2);
    u16*  wupT   = (u16*)alloc((size_t)2 * 2048 * 512 * 2);
    u16*  wqT    = (u16*)alloc((size_t)2 * 1024 * 1024 * 2);
    u16*  wkT    = (u16*)alloc((size_t)2 * 1024 * 1024 * 2);
    u16*  wvT    = (u16*)alloc((size_t)2 * 1024 * 1024 * 2);
    u16*  wdT    = (u16*)alloc((size_t)2 * 512 * 1024 * 2);
    u16*  wfT    = (u16*)alloc((size_t)128 * 512 * 2);
    float* ipre  = (float*)alloc(32768 * 4);
    float* fpre  = (float*)alloc(32768 * 4);
    float* cA    = (float*)alloc(32768 * 4);
    float* MA    = (float*)alloc(32768 * 4);
    float* nF    = (float*)alloc(32768 * 4);

    for (int l = 0; l < 2; l++) {
        cvtT_k<<<dim3(16, 64), 256, 0, stream>>>(w_up + (size_t)l * 512 * 2048, wupT + (size_t)l * 2048 * 512, 512, 2048);
        cvtT_k<<<dim3(32, 32), 256, 0, stream>>>(wq + (size_t)l * 1024 * 1024, wqT + (size_t)l * 1024 * 1024, 1024, 1024);
        cvtT_k<<<dim3(32, 32), 256, 0, stream>>>(wk + (size_t)l * 1024 * 1024, wkT + (size_t)l * 1024 * 1024, 1024, 1024);
        cvtT_k<<<dim3(32, 32), 256, 0, stream>>>(wv + (size_t)l * 1024 * 1024, wvT + (size_t)l * 1024 * 1024, 1024, 1024);
        cvtT_k<<<dim3(32, 16), 256, 0, stream>>>(w_down + (size_t)l * 1024 * 512, wdT + (size_t)l * 512 * 1024, 1024, 512);
    }
    cvtT_k<<<dim3(16, 4), 256, 0, stream>>>(w_fin, wfT, 512, 128);

    const float* xin = x;
    for (int l = 0; l < 2; l++) {
        float* xout = (l == 0) ? xa : xb2;
        ln_fused_k<<<ROWS, 64, 0, stream>>>(xin, ln_g + l * 512, ln_b + l * 512, xln);
        gemm_bf16_k<1><<<dim3(16, 64), 256, 0, stream>>>(
            xln, wupT + (size_t)l * 2048 * 512, 2048, 512, zbuf, xm, nullptr, nullptr, 0);
        conv_k<<<ROWS, 256, 0, stream>>>(xm, conv_w + l * 4 * I_DIM, conv_b + l * I_DIM, cactb);
        gemm_bf16_k<0><<<dim3(8, 64), 256, 0, stream>>>(
            xm, wvT + (size_t)l * 1024 * 1024, 1024, 1024, nullptr, vbf, nullptr, nullptr, 0);
        gemm_bf16_k<0><<<dim3(8, 64), 256, 0, stream>>>(
            cactb, wqT + (size_t)l * 1024 * 1024, 1024, 1024, nullptr, qbf, nullptr, nullptr, 0);
        gemm_bf16_k<0><<<dim3(8, 64), 256, 0, stream>>>(
            cactb, wkT + (size_t)l * 1024 * 1024, 1024, 1024, nullptr, kbf, nullptr, nullptr, 0);
        vt_k<<<dim3(32, 8, 32), 256, 0, stream>>>(vbf, vtg);
        gates_k<<<ROWS / 4, 256, 0, stream>>>(qbf, kbf, vbf,
            w_i + l * 3072 * 4, b_i + l * 4, w_f + l * 3072 * 4, b_f + l * 4, ipre, fpre);
        scan_k<<<32, 1024, 0, stream>>>(ipre, fpre, cA, MA, nF);
        attn_k<<<dim3(16, 4, 8), 256, 0, stream>>>(qbf, kbf, vtg, cA, MA, nF, cactb, zbuf, hbf,
            gn_g + l * I_DIM, skip + l * I_DIM);
        gemm_bf16_k<2><<<dim3(4, 64), 256, 0, stream>>>(
            hbf, wdT + (size_t)l * 512 * 1024, 512, 1024, xout, xoutb,
            b_down + l * 512, xin, 512);
        xin = xout;
    }
    gemm_bf16_k<3><<<dim3(1, 64), 256, 0, stream>>>(
        xoutb, wfT, 128, 512, (float*)d_out, nullptr, b_fin, nullptr, 0);
}